// Round 2
// baseline (1384.040 us; speedup 1.0000x reference)
//
#include <hip/hip_runtime.h>

// Problem constants (reference: B,N1,N2,C,COUT,NS = 2,8192,8192,128,128,16)
#define BB  2
#define NN1 8192
#define NN2 8192
#define CC  128
#define SS  16

typedef unsigned short u16;
typedef short bf16x8 __attribute__((ext_vector_type(8)));
typedef float f32x4  __attribute__((ext_vector_type(4)));

__device__ __forceinline__ u16 f2bf(float f) {
  union { float f; unsigned int u; } v; v.f = f;
  unsigned int r = v.u + 0x7fffu + ((v.u >> 16) & 1u);   // round-to-nearest-even
  return (u16)(r >> 16);
}
__device__ __forceinline__ float bf2f(u16 u) {
  union { float f; unsigned int u; } v; v.u = ((unsigned int)u) << 16;
  return v.f;
}
__device__ __forceinline__ float leaky(float x) { return x >= 0.0f ? x : 0.1f * x; }

// ---------------------------------------------------------------------------
// Convert qk_w / v_w (f32 [128][128]) to bf16 once per launch.
__global__ void k_w2bf(const float* __restrict__ a, const float* __restrict__ b,
                       u16* __restrict__ oa, u16* __restrict__ ob) {
  int e = blockIdx.x * 256 + threadIdx.x;
  if (e < 16384) oa[e] = f2bf(a[e]);
  else if (e < 32768) ob[e - 16384] = f2bf(b[e - 16384]);
}

// ---------------------------------------------------------------------------
// pos-enc stage 1: h[b][n][c] = pos_w[c,:]. xyz[b,:,n] + pos_b[c]; accumulate
// per-(b,group) sum/sumsq (group = 16 channels x N points).
__global__ __launch_bounds__(256)
void k_posenc1(const float* __restrict__ xyz, const float* __restrict__ pw,
               const float* __restrict__ pb, float* __restrict__ h,
               float* __restrict__ stats, int N) {
  int t = threadIdx.x, bx = blockIdx.x;
  int b = bx / (N / 16), n0 = (bx % (N / 16)) * 16;
  int c = t & 127, p = t >> 7;
  float w0 = pw[c * 3], w1 = pw[c * 3 + 1], w2 = pw[c * 3 + 2], bb = pb[c];
  float ls = 0.0f, lss = 0.0f;
  for (int i = 0; i < 8; ++i) {
    int n = n0 + i * 2 + p;
    float x0 = xyz[(b * 3 + 0) * N + n];
    float x1 = xyz[(b * 3 + 1) * N + n];
    float x2 = xyz[(b * 3 + 2) * N + n];
    float hv = w0 * x0 + w1 * x1 + w2 * x2 + bb;
    h[(b * N + n) * 128 + c] = hv;
    ls += hv; lss += hv * hv;
  }
#pragma unroll
  for (int o = 1; o < 16; o <<= 1) { ls += __shfl_xor(ls, o); lss += __shfl_xor(lss, o); }
  if ((t & 15) == 0) {
    int g = c >> 4;
    atomicAdd(&stats[(b * 8 + g) * 2 + 0], ls);
    atomicAdd(&stats[(b * 8 + g) * 2 + 1], lss);
  }
}

// pos-enc stage 2: featp[b][n][c] = feat[b][c][n] + leaky(GN(h)[c]) .
// asbf!=0 -> write bf16 into outb, else f32 into outf.
__global__ __launch_bounds__(256)
void k_posenc2(const float* __restrict__ h, const float* __restrict__ feat,
               const float* __restrict__ gam, const float* __restrict__ bet,
               const float* __restrict__ stats, float* __restrict__ outf,
               u16* __restrict__ outb, int N, int asbf) {
  int t = threadIdx.x, bx = blockIdx.x;
  int b = bx / (N / 16), n0 = (bx % (N / 16)) * 16;
  __shared__ float T[128][17];
  for (int it = 0; it < 8; ++it) {
    int j = t & 15, c = it * 16 + (t >> 4);
    T[c][j] = feat[(b * 128 + c) * N + n0 + j];
  }
  __syncthreads();
  float cnt = 16.0f * (float)N;
  for (int it = 0; it < 8; ++it) {
    int c = t & 127, j = it * 2 + (t >> 7);
    float hv = h[(b * N + n0 + j) * 128 + c];
    int gi = (b * 8 + (c >> 4)) * 2;
    float mu = stats[gi] / cnt;
    float var = stats[gi + 1] / cnt - mu * mu;
    float rs = rsqrtf(var + 1e-5f);
    float x = (hv - mu) * rs * gam[c] + bet[c];
    float r = T[c][j] + leaky(x);
    if (asbf) outb[(b * N + n0 + j) * 128 + c] = f2bf(r);
    else      outf[(b * N + n0 + j) * 128 + c] = r;
  }
}

// ---------------------------------------------------------------------------
// KNN: per block 64 queries, 4 waves each scan a quarter of the 8192
// candidates keeping a register top-16, then merge 4x16 -> 16 in LDS.
__global__ __launch_bounds__(256)
void k_knn(const float* __restrict__ xyz1, const float* __restrict__ xyz2,
           int* __restrict__ idxout) {
  int t = threadIdx.x, w = t >> 6, l = t & 63;
  int bx = blockIdx.x;
  int b = bx >> 7;                       // NN1/64 = 128 blocks per batch
  int qbase = (bx & 127) * 64;
  int q = qbase + l;
  float qx = xyz1[(b * 3 + 0) * NN1 + q];
  float qy = xyz1[(b * 3 + 1) * NN1 + q];
  float qz = xyz1[(b * 3 + 2) * NN1 + q];
  float qs = qx * qx + qy * qy + qz * qz;

  __shared__ float4 ch[4][256];
  __shared__ float mD[64][4][16];
  __shared__ int   mI[64][4][16];

  float dk[16]; int ik[16];
#pragma unroll
  for (int k = 0; k < 16; ++k) { dk[k] = 3.4e38f; ik[k] = 0; }

  int jband = w * 2048;
  for (int it = 0; it < 8; ++it) {
    int cbase = jband + it * 256;
    __syncthreads();
#pragma unroll
    for (int k = 0; k < 4; ++k) {
      int j = cbase + k * 64 + l;
      float x = xyz2[(b * 3 + 0) * NN2 + j];
      float y = xyz2[(b * 3 + 1) * NN2 + j];
      float z = xyz2[(b * 3 + 2) * NN2 + j];
      ch[w][k * 64 + l] = make_float4(x, y, z, x * x + y * y + z * z);
    }
    __syncthreads();
#pragma unroll 4
    for (int i = 0; i < 256; ++i) {
      float4 cv = ch[w][i];
      float d = (qs + cv.w) - 2.0f * (qx * cv.x + qy * cv.y + qz * cv.z);
      if (d < dk[15]) {
        float dd = d; int jj = cbase + i;
#pragma unroll
        for (int k = 0; k < 16; ++k) {
          bool cnd = dd < dk[k];
          float od = dk[k]; int oi = ik[k];
          dk[k] = cnd ? dd : od; ik[k] = cnd ? jj : oi;
          dd = cnd ? od : dd;   jj = cnd ? oi : jj;
        }
      }
    }
  }
#pragma unroll
  for (int k = 0; k < 16; ++k) { mD[l][w][k] = dk[k]; mI[l][w][k] = ik[k]; }
  __syncthreads();
  if (t < 64) {
    int p0 = 0, p1 = 0, p2 = 0, p3 = 0;
    int outbase = (b * NN1 + qbase + t) * 16;
    for (int r = 0; r < 16; ++r) {
      float bd = 3.5e38f; int bw = 0; float v;
      v = (p0 < 16) ? mD[t][0][p0] : 3.6e38f; if (v < bd) { bd = v; bw = 0; }
      v = (p1 < 16) ? mD[t][1][p1] : 3.6e38f; if (v < bd) { bd = v; bw = 1; }
      v = (p2 < 16) ? mD[t][2][p2] : 3.6e38f; if (v < bd) { bd = v; bw = 2; }
      v = (p3 < 16) ? mD[t][3][p3] : 3.6e38f; if (v < bd) { bd = v; bw = 3; }
      int bi;
      if (bw == 0)      { bi = mI[t][0][p0]; ++p0; }
      else if (bw == 1) { bi = mI[t][1][p1]; ++p1; }
      else if (bw == 2) { bi = mI[t][2][p2]; ++p2; }
      else              { bi = mI[t][3][p3]; ++p3; }
      idxout[outbase + r] = bi;
    }
  }
}

// ---------------------------------------------------------------------------
// Fused attention: per workgroup 4 query points x 16 neighbors = 64 columns.
// bf16 MFMA for the two 128x128 projections; everything else f32.
__global__ __launch_bounds__(256, 2)
void k_attn(const float* __restrict__ xyz1, const float* __restrict__ xyz2,
            const float* __restrict__ f1p, const u16* __restrict__ f2p,
            const int* __restrict__ idxb,
            const u16* __restrict__ wq, const u16* __restrict__ wvm,
            const float* __restrict__ eqw, const float* __restrict__ eqb,
            const float* __restrict__ ekw, const float* __restrict__ ekb,
            const float* __restrict__ ev1w, const float* __restrict__ ev1b,
            const float* __restrict__ ev2w, const float* __restrict__ ev2b,
            float* __restrict__ outp) {
  const int t = threadIdx.x;
  const int bx = blockIdx.x;
  const int b = bx / (NN1 / 4);
  const int base = (bx % (NN1 / 4)) * 4;

  __shared__ u16 bufA[64][136];   // qin -> q -> vin
  __shared__ u16 bufB[64][136];   // gathered feat2p (bf16)
  __shared__ float rel3[3][64];
  __shared__ float f1s[4][128];
  __shared__ int jcol[64];
  __shared__ float encw[128][4];  // per-phase encoder params (w0,w1,w2,b)
  __shared__ float attnv[64];

  if (t < 64) jcol[t] = idxb[(b * NN1 + base) * 16 + t];
  if (t >= 128) {
    int c = t - 128;
    encw[c][0] = eqw[c * 3]; encw[c][1] = eqw[c * 3 + 1];
    encw[c][2] = eqw[c * 3 + 2]; encw[c][3] = eqb[c];
  }
  __syncthreads();

  if (t < 64) {
    int j = jcol[t], g = t >> 4;
    rel3[0][t] = xyz2[(b * 3 + 0) * NN2 + j] - xyz1[(b * 3 + 0) * NN1 + base + g];
    rel3[1][t] = xyz2[(b * 3 + 1) * NN2 + j] - xyz1[(b * 3 + 1) * NN1 + base + g];
    rel3[2][t] = xyz2[(b * 3 + 2) * NN2 + j] - xyz1[(b * 3 + 2) * NN1 + base + g];
  }
  for (int e = t; e < 512; e += 256)
    f1s[e >> 7][e & 127] = f1p[(b * NN1 + base + (e >> 7)) * 128 + (e & 127)];
  {
    int n = t >> 2, qtr = t & 3;
    const u16* src = &f2p[(b * NN2 + jcol[n]) * 128 + qtr * 32];
    bf16x8 v0 = *(const bf16x8*)(src + 0);
    bf16x8 v1 = *(const bf16x8*)(src + 8);
    bf16x8 v2 = *(const bf16x8*)(src + 16);
    bf16x8 v3 = *(const bf16x8*)(src + 24);
    *(bf16x8*)&bufB[n][qtr * 32 + 0]  = v0;
    *(bf16x8*)&bufB[n][qtr * 32 + 8]  = v1;
    *(bf16x8*)&bufB[n][qtr * 32 + 16] = v2;
    *(bf16x8*)&bufB[n][qtr * 32 + 24] = v3;
  }
  __syncthreads();

  // Phase B: qin[n][c] = feat1p[c] * leaky(eq_w[c].rel[n] + eq_b[c])
  for (int e = t; e < 2048; e += 256) {
    int n = e >> 5, c0 = (e & 31) * 4;
    float r0 = rel3[0][n], r1 = rel3[1][n], r2 = rel3[2][n];
    const float4 f1v = *(const float4*)&f1s[n >> 4][c0];
    const float f1a[4] = { f1v.x, f1v.y, f1v.z, f1v.w };
    ushort4 o; u16* op = (u16*)&o;
#pragma unroll
    for (int k = 0; k < 4; ++k) {
      float4 w4 = *(const float4*)&encw[c0 + k][0];
      float ev = leaky(w4.x * r0 + w4.y * r1 + w4.z * r2 + w4.w);
      op[k] = f2bf(f1a[k] * ev);
    }
    *(ushort4*)&bufA[n][c0] = o;
  }
  __syncthreads();

  const int w = t >> 6, l = t & 63, l15 = l & 15, l4 = l >> 4;

  // Phase C: q = qk_w @ qin   (MFMA), write q back into bufA as bf16 [n][m]
  {
    f32x4 acc[2][4];
#pragma unroll
    for (int mt = 0; mt < 2; ++mt)
#pragma unroll
      for (int nt = 0; nt < 4; ++nt)
        acc[mt][nt] = (f32x4){0.f, 0.f, 0.f, 0.f};
#pragma unroll
    for (int ks = 0; ks < 4; ++ks) {
      bf16x8 a0 = *(const bf16x8*)&wq[(w * 32 + l15) * 128 + ks * 32 + l4 * 8];
      bf16x8 a1 = *(const bf16x8*)&wq[(w * 32 + 16 + l15) * 128 + ks * 32 + l4 * 8];
#pragma unroll
      for (int nt = 0; nt < 4; ++nt) {
        bf16x8 bv = *(const bf16x8*)&bufA[nt * 16 + l15][ks * 32 + l4 * 8];
        acc[0][nt] = __builtin_amdgcn_mfma_f32_16x16x32_bf16(a0, bv, acc[0][nt], 0, 0, 0);
        acc[1][nt] = __builtin_amdgcn_mfma_f32_16x16x32_bf16(a1, bv, acc[1][nt], 0, 0, 0);
      }
    }
    __syncthreads();
#pragma unroll
    for (int mt = 0; mt < 2; ++mt)
#pragma unroll
      for (int nt = 0; nt < 4; ++nt) {
        int n = nt * 16 + l15;
        int r0 = w * 32 + mt * 16 + l4 * 4;
        ushort4 o; u16* op = (u16*)&o;
#pragma unroll
        for (int i = 0; i < 4; ++i) op[i] = f2bf(acc[mt][nt][i]);
        *(ushort4*)&bufA[n][r0] = o;
      }
  }
  if (t >= 128) {
    int c = t - 128;
    encw[c][0] = ekw[c * 3]; encw[c][1] = ekw[c * 3 + 1];
    encw[c][2] = ekw[c * 3 + 2]; encw[c][3] = ekb[c];
  }
  __syncthreads();

  // Phase D: atten[n] = sum_c q[c][n] * (f2[c][n]*ekc[c][n]) / sqrt(128)
  {
    int n = t >> 2, qtr = t & 3;
    float r0 = rel3[0][n], r1 = rel3[1][n], r2 = rel3[2][n];
    float dot = 0.0f;
#pragma unroll
    for (int cc = 0; cc < 4; ++cc) {
      int c0 = qtr * 32 + cc * 8;
      bf16x8 qv = *(const bf16x8*)&bufA[n][c0];
      bf16x8 fv = *(const bf16x8*)&bufB[n][c0];
#pragma unroll
      for (int k = 0; k < 8; ++k) {
        float4 w4 = *(const float4*)&encw[c0 + k][0];
        float ek = leaky(w4.x * r0 + w4.y * r1 + w4.z * r2 + w4.w);
        dot += bf2f((u16)qv[k]) * (bf2f((u16)fv[k]) * ek);
      }
    }
    dot += __shfl_xor(dot, 1);
    dot += __shfl_xor(dot, 2);
    if (qtr == 0) attnv[n] = dot * 0.08838834764831845f;
  }
  __syncthreads();
  if (t < 64) {                      // softmax over each point's 16 neighbors
    float x = attnv[t];
    float m = x;
#pragma unroll
    for (int o = 1; o < 16; o <<= 1) m = fmaxf(m, __shfl_xor(m, o));
    float e = __expf(x - m);
    float s = e;
#pragma unroll
    for (int o = 1; o < 16; o <<= 1) s += __shfl_xor(s, o);
    attnv[t] = e / s;
  } else if (t >= 128) {
    int c = t - 128;
    encw[c][0] = ev1w[c * 3]; encw[c][1] = ev1w[c * 3 + 1];
    encw[c][2] = ev1w[c * 3 + 2]; encw[c][3] = ev1b[c];
  }
  __syncthreads();

  // Phase E: vin[n][c] = f2[n][c] * ev1c
  for (int e = t; e < 2048; e += 256) {
    int n = e >> 5, c0 = (e & 31) * 4;
    float r0 = rel3[0][n], r1 = rel3[1][n], r2 = rel3[2][n];
    ushort4 fv = *(const ushort4*)&bufB[n][c0];
    const u16 fa[4] = { fv.x, fv.y, fv.z, fv.w };
    ushort4 o; u16* op = (u16*)&o;
#pragma unroll
    for (int k = 0; k < 4; ++k) {
      float4 w4 = *(const float4*)&encw[c0 + k][0];
      float ev = leaky(w4.x * r0 + w4.y * r1 + w4.z * r2 + w4.w);
      op[k] = f2bf(bf2f(fa[k]) * ev);
    }
    *(ushort4*)&bufA[n][c0] = o;
  }
  __syncthreads();

  // Phase F: v = v_w @ vin (MFMA)
  f32x4 acc2[2][4];
#pragma unroll
  for (int mt = 0; mt < 2; ++mt)
#pragma unroll
    for (int nt = 0; nt < 4; ++nt)
      acc2[mt][nt] = (f32x4){0.f, 0.f, 0.f, 0.f};
#pragma unroll
  for (int ks = 0; ks < 4; ++ks) {
    bf16x8 a0 = *(const bf16x8*)&wvm[(w * 32 + l15) * 128 + ks * 32 + l4 * 8];
    bf16x8 a1 = *(const bf16x8*)&wvm[(w * 32 + 16 + l15) * 128 + ks * 32 + l4 * 8];
#pragma unroll
    for (int nt = 0; nt < 4; ++nt) {
      bf16x8 bv = *(const bf16x8*)&bufA[nt * 16 + l15][ks * 32 + l4 * 8];
      acc2[0][nt] = __builtin_amdgcn_mfma_f32_16x16x32_bf16(a0, bv, acc2[0][nt], 0, 0, 0);
      acc2[1][nt] = __builtin_amdgcn_mfma_f32_16x16x32_bf16(a1, bv, acc2[1][nt], 0, 0, 0);
    }
  }
  __syncthreads();
  if (t >= 128) {
    int c = t - 128;
    encw[c][0] = ev2w[c * 3]; encw[c][1] = ev2w[c * 3 + 1];
    encw[c][2] = ev2w[c * 3 + 2]; encw[c][3] = ev2b[c];
  }
  __syncthreads();

  // Phase G: v *= ev2c; out[m][g] = sum_s v*atten + feat1p
#pragma unroll
  for (int mt = 0; mt < 2; ++mt) {
    int m0 = w * 32 + mt * 16 + l4 * 4;
    float4 e0 = *(const float4*)&encw[m0 + 0][0];
    float4 e1 = *(const float4*)&encw[m0 + 1][0];
    float4 e2 = *(const float4*)&encw[m0 + 2][0];
    float4 e3 = *(const float4*)&encw[m0 + 3][0];
#pragma unroll
    for (int nt = 0; nt < 4; ++nt) {
      int n = nt * 16 + l15;
      float r0 = rel3[0][n], r1 = rel3[1][n], r2 = rel3[2][n];
      float aw = attnv[n];
      float s0 = acc2[mt][nt][0] * leaky(e0.x * r0 + e0.y * r1 + e0.z * r2 + e0.w) * aw;
      float s1 = acc2[mt][nt][1] * leaky(e1.x * r0 + e1.y * r1 + e1.z * r2 + e1.w) * aw;
      float s2 = acc2[mt][nt][2] * leaky(e2.x * r0 + e2.y * r1 + e2.z * r2 + e2.w) * aw;
      float s3 = acc2[mt][nt][3] * leaky(e3.x * r0 + e3.y * r1 + e3.z * r2 + e3.w) * aw;
#pragma unroll
      for (int o = 1; o < 16; o <<= 1) {
        s0 += __shfl_xor(s0, o); s1 += __shfl_xor(s1, o);
        s2 += __shfl_xor(s2, o); s3 += __shfl_xor(s3, o);
      }
      if (l15 == 0) {
        const float4 f1v = *(const float4*)&f1s[nt][m0];
        float4 ov = { s0 + f1v.x, s1 + f1v.y, s2 + f1v.z, s3 + f1v.w };
        *(float4*)&outp[(b * NN1 + base + nt) * 128 + m0] = ov;
      }
    }
  }
}

// ---------------------------------------------------------------------------
// FF: h[b][d][n] = ff_w[d,:].feat_new[b][n][:] + ff_b[d]; accumulate GN stats.
__global__ __launch_bounds__(256)
void k_ff(const float* __restrict__ xin, const float* __restrict__ ffw,
          const float* __restrict__ ffb, float* __restrict__ hout,
          float* __restrict__ stats) {
  int t = threadIdx.x, bx = blockIdx.x;
  int b = bx / (NN1 / 32), n0 = (bx % (NN1 / 32)) * 32;
  __shared__ float XT[128][34];
  for (int e = t; e < 4096; e += 256) {
    int c = e & 127, nn = e >> 7;
    XT[c][nn] = xin[(b * NN1 + n0 + nn) * 128 + c];
  }
  __syncthreads();
  int d = t >> 1, nh = t & 1;
  float acc[16];
#pragma unroll
  for (int j = 0; j < 16; ++j) acc[j] = 0.0f;
  for (int c0 = 0; c0 < 128; c0 += 4) {
    float4 w4 = *(const float4*)&ffw[d * 128 + c0];
    const float wa[4] = { w4.x, w4.y, w4.z, w4.w };
#pragma unroll
    for (int k = 0; k < 4; ++k) {
      int c = c0 + k;
#pragma unroll
      for (int j2 = 0; j2 < 8; ++j2) {
        float2 xv = *(const float2*)&XT[c][nh * 16 + j2 * 2];
        acc[j2 * 2 + 0] += wa[k] * xv.x;
        acc[j2 * 2 + 1] += wa[k] * xv.y;
      }
    }
  }
  float bias = ffb[d];
  float ls = 0.0f, lss = 0.0f;
  float out[16];
#pragma unroll
  for (int j = 0; j < 16; ++j) { float h = acc[j] + bias; out[j] = h; ls += h; lss += h * h; }
#pragma unroll
  for (int j4 = 0; j4 < 4; ++j4) {
    float4 o = { out[j4 * 4], out[j4 * 4 + 1], out[j4 * 4 + 2], out[j4 * 4 + 3] };
    *(float4*)&hout[(b * 128 + d) * NN1 + n0 + nh * 16 + j4 * 4] = o;
  }
#pragma unroll
  for (int o = 1; o <= 16; o <<= 1) { ls += __shfl_xor(ls, o); lss += __shfl_xor(lss, o); }
  if ((t & 31) == 0) {
    int g = d >> 4;
    atomicAdd(&stats[(b * 8 + g) * 2 + 0], ls);
    atomicAdd(&stats[(b * 8 + g) * 2 + 1], lss);
  }
}

// Final GN + leaky + f32 store (output part 1: feat_new [B][COUT][N1]).
__global__ __launch_bounds__(256)
void k_final(const float* __restrict__ h, const float* __restrict__ stats,
             const float* __restrict__ g, const float* __restrict__ bt,
             float* __restrict__ out) {
  int e = blockIdx.x * 256 + threadIdx.x;     // < BB*128*NN1 = 2097152
  int d = (e / NN1) & 127;
  int b = e / (128 * NN1);
  int gi = (b * 8 + (d >> 4)) * 2;
  float cnt = 16.0f * (float)NN1;
  float mu = stats[gi] / cnt;
  float var = stats[gi + 1] / cnt - mu * mu;
  float rs = rsqrtf(var + 1e-5f);
  float x = (h[e] - mu) * rs * g[d] + bt[d];
  out[BB * 3 * NN1 + e] = leaky(x);
}

// ---------------------------------------------------------------------------
extern "C" void kernel_launch(void* const* d_in, const int* in_sizes, int n_in,
                              void* d_out, int out_size, void* d_ws, size_t ws_size,
                              hipStream_t stream) {
  const float* xyz1   = (const float*)d_in[0];
  const float* xyz2   = (const float*)d_in[1];
  const float* feat1  = (const float*)d_in[2];
  const float* feat2  = (const float*)d_in[3];
  const float* pos_w  = (const float*)d_in[4];
  const float* pos_b  = (const float*)d_in[5];
  const float* pos_g  = (const float*)d_in[6];
  const float* pos_bt = (const float*)d_in[7];
  const float* ek_w   = (const float*)d_in[8];
  const float* ek_b   = (const float*)d_in[9];
  const float* eq_w   = (const float*)d_in[10];
  const float* eq_b   = (const float*)d_in[11];
  const float* ev1_w  = (const float*)d_in[12];
  const float* ev1_b  = (const float*)d_in[13];
  const float* ev2_w  = (const float*)d_in[14];
  const float* ev2_b  = (const float*)d_in[15];
  const float* qk_w   = (const float*)d_in[16];
  const float* v_w    = (const float*)d_in[17];
  const float* ff_w   = (const float*)d_in[18];
  const float* ff_b   = (const float*)d_in[19];
  const float* ff_g   = (const float*)d_in[20];
  const float* ff_bt  = (const float*)d_in[21];
  (void)in_sizes; (void)n_in; (void)out_size; (void)ws_size;

  char* ws = (char*)d_ws;          // ~29.1 MB used
  float* feat1p   = (float*)(ws);                         // [B][N1][C] f32   8388608 B
  u16*   feat2pb  = (u16*)  (ws + 8388608);               // [B][N2][C] bf16  4194304 B
  float* attn_out = (float*)(ws + 12582912);              // h1 temp, then feat_new [B][N1][C]
  float* h_ff     = (float*)(ws + 20971520);              // h2 temp, then FF out [B][C][N1]
  int*   idxb     = (int*)  (ws + 29360128);              // [B][N1][16]      1048576 B
  u16*   wqk      = (u16*)  (ws + 30408704);              // bf16 qk_w        32768 B
  u16*   wv       = (u16*)  (ws + 30441472);              // bf16 v_w         32768 B
  float* stats    = (float*)(ws + 30474240);              // 96 floats

  hipMemsetAsync(stats, 0, 96 * sizeof(float), stream);
  k_w2bf<<<128, 256, 0, stream>>>(qk_w, v_w, wqk, wv);
  k_posenc1<<<1024, 256, 0, stream>>>(xyz1, pos_w, pos_b, attn_out, stats + 0,  NN1);
  k_posenc1<<<1024, 256, 0, stream>>>(xyz2, pos_w, pos_b, h_ff,     stats + 32, NN2);
  k_posenc2<<<1024, 256, 0, stream>>>(attn_out, feat1, pos_g, pos_bt, stats + 0,
                                      feat1p, (u16*)nullptr, NN1, 0);
  k_posenc2<<<1024, 256, 0, stream>>>(h_ff,     feat2, pos_g, pos_bt, stats + 32,
                                      (float*)nullptr, feat2pb, NN2, 1);
  k_knn<<<256, 256, 0, stream>>>(xyz1, xyz2, idxb);
  k_attn<<<4096, 256, 0, stream>>>(xyz1, xyz2, feat1p, feat2pb, idxb, wqk, wv,
                                   eq_w, eq_b, ek_w, ek_b, ev1_w, ev1_b, ev2_w, ev2_b,
                                   attn_out);
  k_ff<<<512, 256, 0, stream>>>(attn_out, ff_w, ff_b, h_ff, stats + 64);
  hipMemcpyAsync(d_out, xyz1, (size_t)(BB * 3 * NN1) * sizeof(float),
                 hipMemcpyDeviceToDevice, stream);
  k_final<<<8192, 256, 0, stream>>>(h_ff, stats + 64, ff_g, ff_bt, (float*)d_out);
}

// Round 3
// 592.720 us; speedup vs baseline: 2.3351x; 2.3351x over previous
//
#include <hip/hip_runtime.h>

// Problem constants (reference: B,N1,N2,C,COUT,NS = 2,8192,8192,128,128,16)
#define BB  2
#define NN1 8192
#define NN2 8192
#define CC  128
#define SS  16

typedef unsigned short u16;
typedef unsigned int u32;
typedef short bf16x8 __attribute__((ext_vector_type(8)));
typedef float f32x4  __attribute__((ext_vector_type(4)));

__device__ __forceinline__ u16 f2bf(float f) {
  union { float f; unsigned int u; } v; v.f = f;
  unsigned int r = v.u + 0x7fffu + ((v.u >> 16) & 1u);   // round-to-nearest-even
  return (u16)(r >> 16);
}
__device__ __forceinline__ float bf2f(u16 u) {
  union { float f; unsigned int u; } v; v.u = ((unsigned int)u) << 16;
  return v.f;
}
__device__ __forceinline__ float leaky(float x) { return x >= 0.0f ? x : 0.1f * x; }

// ---------------------------------------------------------------------------
// Convert qk_w / v_w (f32 [128][128]) to bf16 once per launch.
__global__ void k_w2bf(const float* __restrict__ a, const float* __restrict__ b,
                       u16* __restrict__ oa, u16* __restrict__ ob) {
  int e = blockIdx.x * 256 + threadIdx.x;
  if (e < 16384) oa[e] = f2bf(a[e]);
  else if (e < 32768) ob[e - 16384] = f2bf(b[e - 16384]);
}

// ---------------------------------------------------------------------------
// pos-enc stage 1: h[b][n][c] = pos_w[c,:]. xyz[b,:,n] + pos_b[c]; accumulate
// per-(b,group) sum/sumsq (group = 16 channels x N points).
__global__ __launch_bounds__(256)
void k_posenc1(const float* __restrict__ xyz, const float* __restrict__ pw,
               const float* __restrict__ pb, float* __restrict__ h,
               float* __restrict__ stats, int N) {
  int t = threadIdx.x, bx = blockIdx.x;
  int b = bx / (N / 16), n0 = (bx % (N / 16)) * 16;
  int c = t & 127, p = t >> 7;
  float w0 = pw[c * 3], w1 = pw[c * 3 + 1], w2 = pw[c * 3 + 2], bb = pb[c];
  float ls = 0.0f, lss = 0.0f;
  for (int i = 0; i < 8; ++i) {
    int n = n0 + i * 2 + p;
    float x0 = xyz[(b * 3 + 0) * N + n];
    float x1 = xyz[(b * 3 + 1) * N + n];
    float x2 = xyz[(b * 3 + 2) * N + n];
    float hv = w0 * x0 + w1 * x1 + w2 * x2 + bb;
    h[(b * N + n) * 128 + c] = hv;
    ls += hv; lss += hv * hv;
  }
#pragma unroll
  for (int o = 1; o < 16; o <<= 1) { ls += __shfl_xor(ls, o); lss += __shfl_xor(lss, o); }
  if ((t & 15) == 0) {
    int g = c >> 4;
    atomicAdd(&stats[(b * 8 + g) * 2 + 0], ls);
    atomicAdd(&stats[(b * 8 + g) * 2 + 1], lss);
  }
}

// pos-enc stage 2: featp[b][n][c] = feat[b][c][n] + leaky(GN(h)[c]) .
// asbf!=0 -> write bf16 into outb, else f32 into outf.
__global__ __launch_bounds__(256)
void k_posenc2(const float* __restrict__ h, const float* __restrict__ feat,
               const float* __restrict__ gam, const float* __restrict__ bet,
               const float* __restrict__ stats, float* __restrict__ outf,
               u16* __restrict__ outb, int N, int asbf) {
  int t = threadIdx.x, bx = blockIdx.x;
  int b = bx / (N / 16), n0 = (bx % (N / 16)) * 16;
  __shared__ float T[128][17];
  for (int it = 0; it < 8; ++it) {
    int j = t & 15, c = it * 16 + (t >> 4);
    T[c][j] = feat[(b * 128 + c) * N + n0 + j];
  }
  __syncthreads();
  float cnt = 16.0f * (float)N;
  for (int it = 0; it < 8; ++it) {
    int c = t & 127, j = it * 2 + (t >> 7);
    float hv = h[(b * N + n0 + j) * 128 + c];
    int gi = (b * 8 + (c >> 4)) * 2;
    float mu = stats[gi] / cnt;
    float var = stats[gi + 1] / cnt - mu * mu;
    float rs = rsqrtf(var + 1e-5f);
    float x = (hv - mu) * rs * gam[c] + bet[c];
    float r = T[c][j] + leaky(x);
    if (asbf) outb[(b * N + n0 + j) * 128 + c] = f2bf(r);
    else      outf[(b * N + n0 + j) * 128 + c] = r;
  }
}

// ---------------------------------------------------------------------------
// KNN. Packed key: (f32 distance^2 bits & 0xFFFFE000) | index (13 bits).
// Smaller key == (smaller distance, then smaller index) — matches top_k.

__device__ __forceinline__ void sort16(u32 (&e)[16]) {
#pragma unroll
  for (int k = 2; k <= 16; k <<= 1) {
#pragma unroll
    for (int j = k >> 1; j > 0; j >>= 1) {
#pragma unroll
      for (int i = 0; i < 16; ++i) {
        int l = i ^ j;
        if (l > i) {
          bool up = ((i & k) == 0);
          u32 x = e[i], y = e[l];
          u32 mn = x < y ? x : y;
          u32 mx = x < y ? y : x;
          e[i] = up ? mn : mx;
          e[l] = up ? mx : mn;
        }
      }
    }
  }
}

// A (sorted asc), S (sorted asc) -> A = lowest 16 of union, sorted asc.
__device__ __forceinline__ void merge16(u32 (&A)[16], const u32 (&S)[16]) {
  u32 t[16];
#pragma unroll
  for (int i = 0; i < 16; ++i) {
    u32 a = A[i], s = S[15 - i];
    t[i] = a < s ? a : s;
  }
#pragma unroll
  for (int j = 8; j > 0; j >>= 1) {
#pragma unroll
    for (int i = 0; i < 16; ++i) {
      if ((i & j) == 0) {
        u32 x = t[i], y = t[i | j];
        t[i] = x < y ? x : y;
        t[i | j] = x < y ? y : x;
      }
    }
  }
#pragma unroll
  for (int i = 0; i < 16; ++i) A[i] = t[i];
}

// Pack xyz planes [b][3][N] -> float4 {x,y,z,|p|^2} [b][N].
__global__ __launch_bounds__(256)
void k_pack(const float* __restrict__ xyz, float4* __restrict__ px, int N) {
  int e = blockIdx.x * 256 + threadIdx.x;      // < BB*N
  int b = e / N, n = e % N;
  float x = xyz[(b * 3 + 0) * N + n];
  float y = xyz[(b * 3 + 1) * N + n];
  float z = xyz[(b * 3 + 2) * N + n];
  px[e] = make_float4(x, y, z, x * x + y * y + z * z);
}

// Stage 1: single-wave blocks. Lane = query (64 per group); block covers one
// 512-candidate slice. Branchless batch-of-16 bitonic top-16 per lane.
// out layout: [b][q][16 slices][16] packed u32, each slice-list sorted asc.
__global__ __launch_bounds__(64)
void k_knn1(const float4* __restrict__ px1, const float4* __restrict__ px2,
            u32* __restrict__ out) {
  int bx = blockIdx.x;                  // b(2) * 128 groups * 16 slices
  int slice = bx & 15, g = (bx >> 4) & 127, b = bx >> 11;
  int l = threadIdx.x;
  int q = g * 64 + l;
  float4 qv = px1[b * NN2 + q];
  u32 A[16];
#pragma unroll
  for (int i = 0; i < 16; ++i) A[i] = 0xFFFFFFFFu;
  const float4* cp = px2 + b * NN2 + slice * 512;
  for (int it = 0; it < 32; ++it) {     // 32 batches of 16 candidates
    u32 S[16];
#pragma unroll
    for (int kk = 0; kk < 16; ++kk) {
      float4 c = cp[it * 16 + kk];      // uniform across lanes -> scalar load
      float m = fmaf(qv.x, c.x, fmaf(qv.y, c.y, qv.z * c.z));
      float d = fmaf(-2.0f, m, qv.w + c.w);
      d = fmaxf(d, 0.0f);
      S[kk] = (__float_as_uint(d) & 0xFFFFE000u) |
              (u32)(slice * 512 + it * 16 + kk);
    }
    sort16(S);
    merge16(A, S);
  }
  u32* op = out + ((b * NN1 + q) * 16 + slice) * 16;
#pragma unroll
  for (int i = 0; i < 4; ++i)
    *(uint4*)&op[i * 4] = make_uint4(A[i * 4], A[i * 4 + 1], A[i * 4 + 2], A[i * 4 + 3]);
}

// Stage 2: one thread per query merges its 16 sorted lists -> final indices.
__global__ __launch_bounds__(256)
void k_knn2(const u32* __restrict__ in, int* __restrict__ idxout) {
  int e = blockIdx.x * 256 + threadIdx.x;    // < BB*NN1 = 16384
  const u32* p = in + (size_t)e * 256;
  u32 A[16];
#pragma unroll
  for (int i = 0; i < 4; ++i) {
    uint4 v = *(const uint4*)&p[i * 4];
    A[i * 4] = v.x; A[i * 4 + 1] = v.y; A[i * 4 + 2] = v.z; A[i * 4 + 3] = v.w;
  }
  for (int s = 1; s < 16; ++s) {
    u32 S[16];
#pragma unroll
    for (int i = 0; i < 4; ++i) {
      uint4 v = *(const uint4*)&p[s * 16 + i * 4];
      S[i * 4] = v.x; S[i * 4 + 1] = v.y; S[i * 4 + 2] = v.z; S[i * 4 + 3] = v.w;
    }
    merge16(A, S);
  }
  int* op = idxout + e * 16;
#pragma unroll
  for (int i = 0; i < 4; ++i) {
    int4 o = make_int4((int)(A[i * 4] & 8191u), (int)(A[i * 4 + 1] & 8191u),
                       (int)(A[i * 4 + 2] & 8191u), (int)(A[i * 4 + 3] & 8191u));
    *(int4*)&op[i * 4] = o;
  }
}

// ---------------------------------------------------------------------------
// Fused attention: per workgroup 4 query points x 16 neighbors = 64 columns.
// bf16 MFMA for the two 128x128 projections; everything else f32.
__global__ __launch_bounds__(256, 2)
void k_attn(const float* __restrict__ xyz1, const float* __restrict__ xyz2,
            const float* __restrict__ f1p, const u16* __restrict__ f2p,
            const int* __restrict__ idxb,
            const u16* __restrict__ wq, const u16* __restrict__ wvm,
            const float* __restrict__ eqw, const float* __restrict__ eqb,
            const float* __restrict__ ekw, const float* __restrict__ ekb,
            const float* __restrict__ ev1w, const float* __restrict__ ev1b,
            const float* __restrict__ ev2w, const float* __restrict__ ev2b,
            float* __restrict__ outp) {
  const int t = threadIdx.x;
  const int bx = blockIdx.x;
  const int b = bx / (NN1 / 4);
  const int base = (bx % (NN1 / 4)) * 4;

  __shared__ u16 bufA[64][136];   // qin -> q -> vin
  __shared__ u16 bufB[64][136];   // gathered feat2p (bf16)
  __shared__ float rel3[3][64];
  __shared__ float f1s[4][128];
  __shared__ int jcol[64];
  __shared__ float encw[128][4];  // per-phase encoder params (w0,w1,w2,b)
  __shared__ float attnv[64];

  if (t < 64) jcol[t] = idxb[(b * NN1 + base) * 16 + t];
  if (t >= 128) {
    int c = t - 128;
    encw[c][0] = eqw[c * 3]; encw[c][1] = eqw[c * 3 + 1];
    encw[c][2] = eqw[c * 3 + 2]; encw[c][3] = eqb[c];
  }
  __syncthreads();

  if (t < 64) {
    int j = jcol[t], g = t >> 4;
    rel3[0][t] = xyz2[(b * 3 + 0) * NN2 + j] - xyz1[(b * 3 + 0) * NN1 + base + g];
    rel3[1][t] = xyz2[(b * 3 + 1) * NN2 + j] - xyz1[(b * 3 + 1) * NN1 + base + g];
    rel3[2][t] = xyz2[(b * 3 + 2) * NN2 + j] - xyz1[(b * 3 + 2) * NN1 + base + g];
  }
  for (int e = t; e < 512; e += 256)
    f1s[e >> 7][e & 127] = f1p[(b * NN1 + base + (e >> 7)) * 128 + (e & 127)];
  {
    int n = t >> 2, qtr = t & 3;
    const u16* src = &f2p[(b * NN2 + jcol[n]) * 128 + qtr * 32];
    bf16x8 v0 = *(const bf16x8*)(src + 0);
    bf16x8 v1 = *(const bf16x8*)(src + 8);
    bf16x8 v2 = *(const bf16x8*)(src + 16);
    bf16x8 v3 = *(const bf16x8*)(src + 24);
    *(bf16x8*)&bufB[n][qtr * 32 + 0]  = v0;
    *(bf16x8*)&bufB[n][qtr * 32 + 8]  = v1;
    *(bf16x8*)&bufB[n][qtr * 32 + 16] = v2;
    *(bf16x8*)&bufB[n][qtr * 32 + 24] = v3;
  }
  __syncthreads();

  // Phase B: qin[n][c] = feat1p[c] * leaky(eq_w[c].rel[n] + eq_b[c])
  for (int e = t; e < 2048; e += 256) {
    int n = e >> 5, c0 = (e & 31) * 4;
    float r0 = rel3[0][n], r1 = rel3[1][n], r2 = rel3[2][n];
    const float4 f1v = *(const float4*)&f1s[n >> 4][c0];
    const float f1a[4] = { f1v.x, f1v.y, f1v.z, f1v.w };
    ushort4 o; u16* op = (u16*)&o;
#pragma unroll
    for (int k = 0; k < 4; ++k) {
      float4 w4 = *(const float4*)&encw[c0 + k][0];
      float ev = leaky(w4.x * r0 + w4.y * r1 + w4.z * r2 + w4.w);
      op[k] = f2bf(f1a[k] * ev);
    }
    *(ushort4*)&bufA[n][c0] = o;
  }
  __syncthreads();

  const int w = t >> 6, l = t & 63, l15 = l & 15, l4 = l >> 4;

  // Phase C: q = qk_w @ qin   (MFMA), write q back into bufA as bf16 [n][m]
  {
    f32x4 acc[2][4];
#pragma unroll
    for (int mt = 0; mt < 2; ++mt)
#pragma unroll
      for (int nt = 0; nt < 4; ++nt)
        acc[mt][nt] = (f32x4){0.f, 0.f, 0.f, 0.f};
#pragma unroll
    for (int ks = 0; ks < 4; ++ks) {
      bf16x8 a0 = *(const bf16x8*)&wq[(w * 32 + l15) * 128 + ks * 32 + l4 * 8];
      bf16x8 a1 = *(const bf16x8*)&wq[(w * 32 + 16 + l15) * 128 + ks * 32 + l4 * 8];
#pragma unroll
      for (int nt = 0; nt < 4; ++nt) {
        bf16x8 bv = *(const bf16x8*)&bufA[nt * 16 + l15][ks * 32 + l4 * 8];
        acc[0][nt] = __builtin_amdgcn_mfma_f32_16x16x32_bf16(a0, bv, acc[0][nt], 0, 0, 0);
        acc[1][nt] = __builtin_amdgcn_mfma_f32_16x16x32_bf16(a1, bv, acc[1][nt], 0, 0, 0);
      }
    }
    __syncthreads();
#pragma unroll
    for (int mt = 0; mt < 2; ++mt)
#pragma unroll
      for (int nt = 0; nt < 4; ++nt) {
        int n = nt * 16 + l15;
        int r0 = w * 32 + mt * 16 + l4 * 4;
        ushort4 o; u16* op = (u16*)&o;
#pragma unroll
        for (int i = 0; i < 4; ++i) op[i] = f2bf(acc[mt][nt][i]);
        *(ushort4*)&bufA[n][r0] = o;
      }
  }
  if (t >= 128) {
    int c = t - 128;
    encw[c][0] = ekw[c * 3]; encw[c][1] = ekw[c * 3 + 1];
    encw[c][2] = ekw[c * 3 + 2]; encw[c][3] = ekb[c];
  }
  __syncthreads();

  // Phase D: atten[n] = sum_c q[c][n] * (f2[c][n]*ekc[c][n]) / sqrt(128)
  {
    int n = t >> 2, qtr = t & 3;
    float r0 = rel3[0][n], r1 = rel3[1][n], r2 = rel3[2][n];
    float dot = 0.0f;
#pragma unroll
    for (int cc = 0; cc < 4; ++cc) {
      int c0 = qtr * 32 + cc * 8;
      bf16x8 qv = *(const bf16x8*)&bufA[n][c0];
      bf16x8 fv = *(const bf16x8*)&bufB[n][c0];
#pragma unroll
      for (int k = 0; k < 8; ++k) {
        float4 w4 = *(const float4*)&encw[c0 + k][0];
        float ek = leaky(w4.x * r0 + w4.y * r1 + w4.z * r2 + w4.w);
        dot += bf2f((u16)qv[k]) * (bf2f((u16)fv[k]) * ek);
      }
    }
    dot += __shfl_xor(dot, 1);
    dot += __shfl_xor(dot, 2);
    if (qtr == 0) attnv[n] = dot * 0.08838834764831845f;
  }
  __syncthreads();
  if (t < 64) {                      // softmax over each point's 16 neighbors
    float x = attnv[t];
    float m = x;
#pragma unroll
    for (int o = 1; o < 16; o <<= 1) m = fmaxf(m, __shfl_xor(m, o));
    float e = __expf(x - m);
    float s = e;
#pragma unroll
    for (int o = 1; o < 16; o <<= 1) s += __shfl_xor(s, o);
    attnv[t] = e / s;
  } else if (t >= 128) {
    int c = t - 128;
    encw[c][0] = ev1w[c * 3]; encw[c][1] = ev1w[c * 3 + 1];
    encw[c][2] = ev1w[c * 3 + 2]; encw[c][3] = ev1b[c];
  }
  __syncthreads();

  // Phase E: vin[n][c] = f2[n][c] * ev1c
  for (int e = t; e < 2048; e += 256) {
    int n = e >> 5, c0 = (e & 31) * 4;
    float r0 = rel3[0][n], r1 = rel3[1][n], r2 = rel3[2][n];
    ushort4 fv = *(const ushort4*)&bufB[n][c0];
    const u16 fa[4] = { fv.x, fv.y, fv.z, fv.w };
    ushort4 o; u16* op = (u16*)&o;
#pragma unroll
    for (int k = 0; k < 4; ++k) {
      float4 w4 = *(const float4*)&encw[c0 + k][0];
      float ev = leaky(w4.x * r0 + w4.y * r1 + w4.z * r2 + w4.w);
      op[k] = f2bf(bf2f(fa[k]) * ev);
    }
    *(ushort4*)&bufA[n][c0] = o;
  }
  __syncthreads();

  // Phase F: v = v_w @ vin (MFMA)
  f32x4 acc2[2][4];
#pragma unroll
  for (int mt = 0; mt < 2; ++mt)
#pragma unroll
    for (int nt = 0; nt < 4; ++nt)
      acc2[mt][nt] = (f32x4){0.f, 0.f, 0.f, 0.f};
#pragma unroll
  for (int ks = 0; ks < 4; ++ks) {
    bf16x8 a0 = *(const bf16x8*)&wvm[(w * 32 + l15) * 128 + ks * 32 + l4 * 8];
    bf16x8 a1 = *(const bf16x8*)&wvm[(w * 32 + 16 + l15) * 128 + ks * 32 + l4 * 8];
#pragma unroll
    for (int nt = 0; nt < 4; ++nt) {
      bf16x8 bv = *(const bf16x8*)&bufA[nt * 16 + l15][ks * 32 + l4 * 8];
      acc2[0][nt] = __builtin_amdgcn_mfma_f32_16x16x32_bf16(a0, bv, acc2[0][nt], 0, 0, 0);
      acc2[1][nt] = __builtin_amdgcn_mfma_f32_16x16x32_bf16(a1, bv, acc2[1][nt], 0, 0, 0);
    }
  }
  __syncthreads();
  if (t >= 128) {
    int c = t - 128;
    encw[c][0] = ev2w[c * 3]; encw[c][1] = ev2w[c * 3 + 1];
    encw[c][2] = ev2w[c * 3 + 2]; encw[c][3] = ev2b[c];
  }
  __syncthreads();

  // Phase G: v *= ev2c; out[m][g] = sum_s v*atten + feat1p
#pragma unroll
  for (int mt = 0; mt < 2; ++mt) {
    int m0 = w * 32 + mt * 16 + l4 * 4;
    float4 e0 = *(const float4*)&encw[m0 + 0][0];
    float4 e1 = *(const float4*)&encw[m0 + 1][0];
    float4 e2 = *(const float4*)&encw[m0 + 2][0];
    float4 e3 = *(const float4*)&encw[m0 + 3][0];
#pragma unroll
    for (int nt = 0; nt < 4; ++nt) {
      int n = nt * 16 + l15;
      float r0 = rel3[0][n], r1 = rel3[1][n], r2 = rel3[2][n];
      float aw = attnv[n];
      float s0 = acc2[mt][nt][0] * leaky(e0.x * r0 + e0.y * r1 + e0.z * r2 + e0.w) * aw;
      float s1 = acc2[mt][nt][1] * leaky(e1.x * r0 + e1.y * r1 + e1.z * r2 + e1.w) * aw;
      float s2 = acc2[mt][nt][2] * leaky(e2.x * r0 + e2.y * r1 + e2.z * r2 + e2.w) * aw;
      float s3 = acc2[mt][nt][3] * leaky(e3.x * r0 + e3.y * r1 + e3.z * r2 + e3.w) * aw;
#pragma unroll
      for (int o = 1; o < 16; o <<= 1) {
        s0 += __shfl_xor(s0, o); s1 += __shfl_xor(s1, o);
        s2 += __shfl_xor(s2, o); s3 += __shfl_xor(s3, o);
      }
      if (l15 == 0) {
        const float4 f1v = *(const float4*)&f1s[nt][m0];
        float4 ov = { s0 + f1v.x, s1 + f1v.y, s2 + f1v.z, s3 + f1v.w };
        *(float4*)&outp[(b * NN1 + base + nt) * 128 + m0] = ov;
      }
    }
  }
}

// ---------------------------------------------------------------------------
// FF: h[b][d][n] = ff_w[d,:].feat_new[b][n][:] + ff_b[d]; accumulate GN stats.
__global__ __launch_bounds__(256)
void k_ff(const float* __restrict__ xin, const float* __restrict__ ffw,
          const float* __restrict__ ffb, float* __restrict__ hout,
          float* __restrict__ stats) {
  int t = threadIdx.x, bx = blockIdx.x;
  int b = bx / (NN1 / 32), n0 = (bx % (NN1 / 32)) * 32;
  __shared__ float XT[128][34];
  for (int e = t; e < 4096; e += 256) {
    int c = e & 127, nn = e >> 7;
    XT[c][nn] = xin[(b * NN1 + n0 + nn) * 128 + c];
  }
  __syncthreads();
  int d = t >> 1, nh = t & 1;
  float acc[16];
#pragma unroll
  for (int j = 0; j < 16; ++j) acc[j] = 0.0f;
  for (int c0 = 0; c0 < 128; c0 += 4) {
    float4 w4 = *(const float4*)&ffw[d * 128 + c0];
    const float wa[4] = { w4.x, w4.y, w4.z, w4.w };
#pragma unroll
    for (int k = 0; k < 4; ++k) {
      int c = c0 + k;
#pragma unroll
      for (int j2 = 0; j2 < 8; ++j2) {
        float2 xv = *(const float2*)&XT[c][nh * 16 + j2 * 2];
        acc[j2 * 2 + 0] += wa[k] * xv.x;
        acc[j2 * 2 + 1] += wa[k] * xv.y;
      }
    }
  }
  float bias = ffb[d];
  float ls = 0.0f, lss = 0.0f;
  float out[16];
#pragma unroll
  for (int j = 0; j < 16; ++j) { float h = acc[j] + bias; out[j] = h; ls += h; lss += h * h; }
#pragma unroll
  for (int j4 = 0; j4 < 4; ++j4) {
    float4 o = { out[j4 * 4], out[j4 * 4 + 1], out[j4 * 4 + 2], out[j4 * 4 + 3] };
    *(float4*)&hout[(b * 128 + d) * NN1 + n0 + nh * 16 + j4 * 4] = o;
  }
#pragma unroll
  for (int o = 1; o <= 16; o <<= 1) { ls += __shfl_xor(ls, o); lss += __shfl_xor(lss, o); }
  if ((t & 31) == 0) {
    int g = d >> 4;
    atomicAdd(&stats[(b * 8 + g) * 2 + 0], ls);
    atomicAdd(&stats[(b * 8 + g) * 2 + 1], lss);
  }
}

// Final GN + leaky + f32 store (output part 1: feat_new [B][COUT][N1]).
__global__ __launch_bounds__(256)
void k_final(const float* __restrict__ h, const float* __restrict__ stats,
             const float* __restrict__ g, const float* __restrict__ bt,
             float* __restrict__ out) {
  int e = blockIdx.x * 256 + threadIdx.x;     // < BB*128*NN1 = 2097152
  int d = (e / NN1) & 127;
  int b = e / (128 * NN1);
  int gi = (b * 8 + (d >> 4)) * 2;
  float cnt = 16.0f * (float)NN1;
  float mu = stats[gi] / cnt;
  float var = stats[gi + 1] / cnt - mu * mu;
  float rs = rsqrtf(var + 1e-5f);
  float x = (h[e] - mu) * rs * g[d] + bt[d];
  out[BB * 3 * NN1 + e] = leaky(x);
}

// ---------------------------------------------------------------------------
extern "C" void kernel_launch(void* const* d_in, const int* in_sizes, int n_in,
                              void* d_out, int out_size, void* d_ws, size_t ws_size,
                              hipStream_t stream) {
  const float* xyz1   = (const float*)d_in[0];
  const float* xyz2   = (const float*)d_in[1];
  const float* feat1  = (const float*)d_in[2];
  const float* feat2  = (const float*)d_in[3];
  const float* pos_w  = (const float*)d_in[4];
  const float* pos_b  = (const float*)d_in[5];
  const float* pos_g  = (const float*)d_in[6];
  const float* pos_bt = (const float*)d_in[7];
  const float* ek_w   = (const float*)d_in[8];
  const float* ek_b   = (const float*)d_in[9];
  const float* eq_w   = (const float*)d_in[10];
  const float* eq_b   = (const float*)d_in[11];
  const float* ev1_w  = (const float*)d_in[12];
  const float* ev1_b  = (const float*)d_in[13];
  const float* ev2_w  = (const float*)d_in[14];
  const float* ev2_b  = (const float*)d_in[15];
  const float* qk_w   = (const float*)d_in[16];
  const float* v_w    = (const float*)d_in[17];
  const float* ff_w   = (const float*)d_in[18];
  const float* ff_b   = (const float*)d_in[19];
  const float* ff_g   = (const float*)d_in[20];
  const float* ff_bt  = (const float*)d_in[21];
  (void)in_sizes; (void)n_in; (void)out_size; (void)ws_size;

  char* ws = (char*)d_ws;          // ~29.6 MB used
  float* feat1p   = (float*)(ws);                         // [B][N1][C] f32   8388608 B
  u16*   feat2pb  = (u16*)  (ws + 8388608);               // [B][N2][C] bf16  4194304 B
  float* attn_out = (float*)(ws + 12582912);              // h1 temp / knn_tmp / feat_new
  float* h_ff     = (float*)(ws + 20971520);              // h2 temp / knn_tmp / FF out
  u32*   knn_tmp  = (u32*)  (ws + 12582912);              // [B][N1][16][16] u32 = 16 MiB
  int*   idxb     = (int*)  (ws + 29360128);              // [B][N1][16]      1048576 B
  u16*   wqk      = (u16*)  (ws + 30408704);              // bf16 qk_w        32768 B
  u16*   wv       = (u16*)  (ws + 30441472);              // bf16 v_w         32768 B
  float* stats    = (float*)(ws + 30474240);              // 96 floats (384 B)
  float4* px1     = (float4*)(ws + 30474624);             // [B][N1] packed   262144 B
  float4* px2     = (float4*)(ws + 30736768);             // [B][N2] packed   262144 B

  hipMemsetAsync(stats, 0, 96 * sizeof(float), stream);
  k_w2bf<<<128, 256, 0, stream>>>(qk_w, v_w, wqk, wv);
  k_pack<<<64, 256, 0, stream>>>(xyz1, px1, NN1);
  k_pack<<<64, 256, 0, stream>>>(xyz2, px2, NN2);
  k_posenc1<<<1024, 256, 0, stream>>>(xyz1, pos_w, pos_b, attn_out, stats + 0,  NN1);
  k_posenc1<<<1024, 256, 0, stream>>>(xyz2, pos_w, pos_b, h_ff,     stats + 32, NN2);
  k_posenc2<<<1024, 256, 0, stream>>>(attn_out, feat1, pos_g, pos_bt, stats + 0,
                                      feat1p, (u16*)nullptr, NN1, 0);
  k_posenc2<<<1024, 256, 0, stream>>>(h_ff,     feat2, pos_g, pos_bt, stats + 32,
                                      (float*)nullptr, feat2pb, NN2, 1);
  // KNN (reuses the dead pos-enc temp region as scratch)
  k_knn1<<<4096, 64, 0, stream>>>(px1, px2, knn_tmp);
  k_knn2<<<64, 256, 0, stream>>>(knn_tmp, idxb);
  k_attn<<<4096, 256, 0, stream>>>(xyz1, xyz2, feat1p, feat2pb, idxb, wqk, wv,
                                   eq_w, eq_b, ek_w, ek_b, ev1_w, ev1_b, ev2_w, ev2_b,
                                   attn_out);
  k_ff<<<512, 256, 0, stream>>>(attn_out, ff_w, ff_b, h_ff, stats + 64);
  hipMemcpyAsync(d_out, xyz1, (size_t)(BB * 3 * NN1) * sizeof(float),
                 hipMemcpyDeviceToDevice, stream);
  k_final<<<8192, 256, 0, stream>>>(h_ff, stats + 64, ff_g, ff_bt, (float*)d_out);
}

// Round 4
// 473.351 us; speedup vs baseline: 2.9239x; 1.2522x over previous
//
#include <hip/hip_runtime.h>
#include <hip/hip_bf16.h>

// Problem constants (reference: B,N1,N2,C,COUT,NS = 2,8192,8192,128,128,16)
#define BB  2
#define NN1 8192
#define NN2 8192
#define CC  128
#define SS  16

typedef unsigned short u16;
typedef unsigned int u32;
typedef short bf16x8 __attribute__((ext_vector_type(8)));
typedef float f32x4  __attribute__((ext_vector_type(4)));

__device__ __forceinline__ u16 f2bf(float f) {
  __hip_bfloat16 h = __float2bfloat16(f);      // RNE; compiles to cvt_pk pairs
  return *(u16*)&h;
}
__device__ __forceinline__ float bf2f(u16 u) {
  union { float f; unsigned int u; } v; v.u = ((unsigned int)u) << 16;
  return v.f;
}
__device__ __forceinline__ float leaky(float x) { return x >= 0.0f ? x : 0.1f * x; }

// ---------------------------------------------------------------------------
// Convert qk_w / v_w (f32 [128][128]) to bf16 once per launch.
__global__ void k_w2bf(const float* __restrict__ a, const float* __restrict__ b,
                       u16* __restrict__ oa, u16* __restrict__ ob) {
  int e = blockIdx.x * 256 + threadIdx.x;
  if (e < 16384) oa[e] = f2bf(a[e]);
  else if (e < 32768) ob[e - 16384] = f2bf(b[e - 16384]);
}

// ---------------------------------------------------------------------------
// pos-enc stage 1: h[b][n][c] = pos_w[c,:]. xyz[b,:,n] + pos_b[c]; accumulate
// per-(b,group) sum/sumsq (group = 16 channels x N points).
__global__ __launch_bounds__(256)
void k_posenc1(const float* __restrict__ xyz, const float* __restrict__ pw,
               const float* __restrict__ pb, float* __restrict__ h,
               float* __restrict__ stats, int N) {
  int t = threadIdx.x, bx = blockIdx.x;
  int b = bx / (N / 16), n0 = (bx % (N / 16)) * 16;
  int c = t & 127, p = t >> 7;
  float w0 = pw[c * 3], w1 = pw[c * 3 + 1], w2 = pw[c * 3 + 2], bb = pb[c];
  float ls = 0.0f, lss = 0.0f;
  for (int i = 0; i < 8; ++i) {
    int n = n0 + i * 2 + p;
    float x0 = xyz[(b * 3 + 0) * N + n];
    float x1 = xyz[(b * 3 + 1) * N + n];
    float x2 = xyz[(b * 3 + 2) * N + n];
    float hv = w0 * x0 + w1 * x1 + w2 * x2 + bb;
    h[(b * N + n) * 128 + c] = hv;
    ls += hv; lss += hv * hv;
  }
#pragma unroll
  for (int o = 1; o < 16; o <<= 1) { ls += __shfl_xor(ls, o); lss += __shfl_xor(lss, o); }
  if ((t & 15) == 0) {
    int g = c >> 4;
    atomicAdd(&stats[(b * 8 + g) * 2 + 0], ls);
    atomicAdd(&stats[(b * 8 + g) * 2 + 1], lss);
  }
}

// pos-enc stage 2: featp[b][n][c] = feat[b][c][n] + leaky(GN(h)[c]) .
// asbf!=0 -> write bf16 into outb, else f32 into outf.
__global__ __launch_bounds__(256)
void k_posenc2(const float* __restrict__ h, const float* __restrict__ feat,
               const float* __restrict__ gam, const float* __restrict__ bet,
               const float* __restrict__ stats, float* __restrict__ outf,
               u16* __restrict__ outb, int N, int asbf) {
  int t = threadIdx.x, bx = blockIdx.x;
  int b = bx / (N / 16), n0 = (bx % (N / 16)) * 16;
  __shared__ float T[128][17];
  for (int it = 0; it < 8; ++it) {
    int j = t & 15, c = it * 16 + (t >> 4);
    T[c][j] = feat[(b * 128 + c) * N + n0 + j];
  }
  __syncthreads();
  float cnt = 16.0f * (float)N;
  for (int it = 0; it < 8; ++it) {
    int c = t & 127, j = it * 2 + (t >> 7);
    float hv = h[(b * N + n0 + j) * 128 + c];
    int gi = (b * 8 + (c >> 4)) * 2;
    float mu = stats[gi] / cnt;
    float var = stats[gi + 1] / cnt - mu * mu;
    float rs = rsqrtf(var + 1e-5f);
    float x = (hv - mu) * rs * gam[c] + bet[c];
    float r = T[c][j] + leaky(x);
    if (asbf) outb[(b * N + n0 + j) * 128 + c] = f2bf(r);
    else      outf[(b * N + n0 + j) * 128 + c] = r;
  }
}

// ---------------------------------------------------------------------------
// KNN. Packed key: (f32 distance^2 bits & 0xFFFFE000) | index (13 bits).

__device__ __forceinline__ void sort16(u32 (&e)[16]) {
#pragma unroll
  for (int k = 2; k <= 16; k <<= 1) {
#pragma unroll
    for (int j = k >> 1; j > 0; j >>= 1) {
#pragma unroll
      for (int i = 0; i < 16; ++i) {
        int l = i ^ j;
        if (l > i) {
          bool up = ((i & k) == 0);
          u32 x = e[i], y = e[l];
          u32 mn = x < y ? x : y;
          u32 mx = x < y ? y : x;
          e[i] = up ? mn : mx;
          e[l] = up ? mx : mn;
        }
      }
    }
  }
}

__device__ __forceinline__ void merge16(u32 (&A)[16], const u32 (&S)[16]) {
  u32 t[16];
#pragma unroll
  for (int i = 0; i < 16; ++i) {
    u32 a = A[i], s = S[15 - i];
    t[i] = a < s ? a : s;
  }
#pragma unroll
  for (int j = 8; j > 0; j >>= 1) {
#pragma unroll
    for (int i = 0; i < 16; ++i) {
      if ((i & j) == 0) {
        u32 x = t[i], y = t[i | j];
        t[i] = x < y ? x : y;
        t[i | j] = x < y ? y : x;
      }
    }
  }
#pragma unroll
  for (int i = 0; i < 16; ++i) A[i] = t[i];
}

__global__ __launch_bounds__(256)
void k_pack(const float* __restrict__ xyz, float4* __restrict__ px, int N) {
  int e = blockIdx.x * 256 + threadIdx.x;
  int b = e / N, n = e % N;
  float x = xyz[(b * 3 + 0) * N + n];
  float y = xyz[(b * 3 + 1) * N + n];
  float z = xyz[(b * 3 + 2) * N + n];
  px[e] = make_float4(x, y, z, x * x + y * y + z * z);
}

__global__ __launch_bounds__(64)
void k_knn1(const float4* __restrict__ px1, const float4* __restrict__ px2,
            u32* __restrict__ out) {
  int bx = blockIdx.x;
  int slice = bx & 15, g = (bx >> 4) & 127, b = bx >> 11;
  int l = threadIdx.x;
  int q = g * 64 + l;
  float4 qv = px1[b * NN2 + q];
  u32 A[16];
#pragma unroll
  for (int i = 0; i < 16; ++i) A[i] = 0xFFFFFFFFu;
  const float4* cp = px2 + b * NN2 + slice * 512;
  for (int it = 0; it < 32; ++it) {
    u32 S[16];
#pragma unroll
    for (int kk = 0; kk < 16; ++kk) {
      float4 c = cp[it * 16 + kk];
      float m = fmaf(qv.x, c.x, fmaf(qv.y, c.y, qv.z * c.z));
      float d = fmaf(-2.0f, m, qv.w + c.w);
      d = fmaxf(d, 0.0f);
      S[kk] = (__float_as_uint(d) & 0xFFFFE000u) |
              (u32)(slice * 512 + it * 16 + kk);
    }
    sort16(S);
    merge16(A, S);
  }
  u32* op = out + ((b * NN1 + q) * 16 + slice) * 16;
#pragma unroll
  for (int i = 0; i < 4; ++i)
    *(uint4*)&op[i * 4] = make_uint4(A[i * 4], A[i * 4 + 1], A[i * 4 + 2], A[i * 4 + 3]);
}

__global__ __launch_bounds__(256)
void k_knn2(const u32* __restrict__ in, int* __restrict__ idxout) {
  int e = blockIdx.x * 256 + threadIdx.x;
  const u32* p = in + (size_t)e * 256;
  u32 A[16];
#pragma unroll
  for (int i = 0; i < 4; ++i) {
    uint4 v = *(const uint4*)&p[i * 4];
    A[i * 4] = v.x; A[i * 4 + 1] = v.y; A[i * 4 + 2] = v.z; A[i * 4 + 3] = v.w;
  }
  for (int s = 1; s < 16; ++s) {
    u32 S[16];
#pragma unroll
    for (int i = 0; i < 4; ++i) {
      uint4 v = *(const uint4*)&p[s * 16 + i * 4];
      S[i * 4] = v.x; S[i * 4 + 1] = v.y; S[i * 4 + 2] = v.z; S[i * 4 + 3] = v.w;
    }
    merge16(A, S);
  }
  int* op = idxout + e * 16;
#pragma unroll
  for (int i = 0; i < 4; ++i) {
    int4 o = make_int4((int)(A[i * 4] & 8191u), (int)(A[i * 4 + 1] & 8191u),
                       (int)(A[i * 4 + 2] & 8191u), (int)(A[i * 4 + 3] & 8191u));
    *(int4*)&op[i * 4] = o;
  }
}

// ---------------------------------------------------------------------------
// Fused attention, wave-local: each wave owns 2 query points (2 MFMA column
// tiles of 16 samples), full M=128. One barrier; B-fragments built in
// registers; f2 gather staged in XOR-swizzled LDS.
__global__ __launch_bounds__(256, 3)
void k_attn(const float* __restrict__ xyz1, const float* __restrict__ xyz2,
            const float* __restrict__ f1p, const u16* __restrict__ f2p,
            const int* __restrict__ idxb,
            const u16* __restrict__ wq, const u16* __restrict__ wvm,
            const float* __restrict__ eqw, const float* __restrict__ eqb,
            const float* __restrict__ ekw, const float* __restrict__ ekb,
            const float* __restrict__ ev1w, const float* __restrict__ ev1b,
            const float* __restrict__ ev2w, const float* __restrict__ ev2b,
            float* __restrict__ outp) {
  const int t = threadIdx.x, bx = blockIdx.x;
  const int b = bx >> 10;              // 1024 blocks per batch
  const int base8 = (bx & 1023) * 8;   // 8 points per block
  const int w = t >> 6, l = t & 63, l15 = l & 15, l4 = l >> 4;

  __shared__ u16 bufB[128 * 128];      // gathered f2 (bf16), XOR-swizzled
  __shared__ float encS[4 * 128 * 5];  // eq,ek,ev1,ev2: [c][w0,w1,w2,b,(pad)]
  __shared__ float f1s[8 * 132];       // feat1p rows for the 8 points

  // stage encoder params + f1 rows
  for (int i = t; i < 512; i += 256) {
    int e = i >> 7, c = i & 127;
    const float* wsrc = (e == 0) ? eqw : (e == 1) ? ekw : (e == 2) ? ev1w : ev2w;
    const float* bsrc = (e == 0) ? eqb : (e == 1) ? ekb : (e == 2) ? ev1b : ev2b;
    float* dst = &encS[(e * 128 + c) * 5];
    dst[0] = wsrc[c * 3]; dst[1] = wsrc[c * 3 + 1];
    dst[2] = wsrc[c * 3 + 2]; dst[3] = bsrc[c];
  }
  for (int i = t; i < 1024; i += 256) {
    int p = i >> 7, c = i & 127;
    f1s[p * 132 + c] = f1p[(size_t)((b * NN1 + base8 + p)) * 128 + c];
  }

  // gather this wave's 32 neighbor rows (2 points x 16 samples) into bufB
  {
    int rr = l >> 1, hh = l & 1;
    int pl = rr >> 4, s = rr & 15;
    int j = idxb[(b * NN1 + base8 + w * 2 + pl) * 16 + s];
    const u16* src = f2p + (size_t)(b * NN2 + j) * 128 + hh * 64;
    int row = w * 32 + rr;
    u16* drow = &bufB[row * 128];
    int sw = (row & 7) << 3;
#pragma unroll
    for (int k = 0; k < 8; ++k) {
      bf16x8 v = *(const bf16x8*)(src + k * 8);
      *(bf16x8*)&drow[(hh * 64 + k * 8) ^ sw] = v;
    }
  }

  // per-lane relative coords for its (point nt, sample l15)
  float r0[2], r1[2], r2[2];
#pragma unroll
  for (int nt = 0; nt < 2; ++nt) {
    int pt = base8 + w * 2 + nt;
    int j = idxb[(b * NN1 + pt) * 16 + l15];
    r0[nt] = xyz2[(b * 3 + 0) * NN2 + j] - xyz1[(b * 3 + 0) * NN1 + pt];
    r1[nt] = xyz2[(b * 3 + 1) * NN2 + j] - xyz1[(b * 3 + 1) * NN1 + pt];
    r2[nt] = xyz2[(b * 3 + 2) * NN2 + j] - xyz1[(b * 3 + 2) * NN1 + pt];
  }
  __syncthreads();

  const int swl = (l15 & 7) << 3;      // read-side XOR swizzle

  // ---- q = Wq @ (f1 * eqc): B-fragments in registers, acc in f32 ----
  f32x4 acc[8][2];
#pragma unroll
  for (int mt = 0; mt < 8; ++mt)
#pragma unroll
    for (int nt = 0; nt < 2; ++nt)
      acc[mt][nt] = (f32x4){0.f, 0.f, 0.f, 0.f};

#pragma unroll
  for (int ks = 0; ks < 4; ++ks) {
    bf16x8 bq[2];
#pragma unroll
    for (int nt = 0; nt < 2; ++nt) {
#pragma unroll
      for (int j = 0; j < 8; ++j) {
        int c = ks * 32 + l4 * 8 + j;
        const float* ew = &encS[(0 * 128 + c) * 5];
        float e = leaky(ew[0] * r0[nt] + ew[1] * r1[nt] + ew[2] * r2[nt] + ew[3]);
        bq[nt][j] = (short)f2bf(f1s[(w * 2 + nt) * 132 + c] * e);
      }
    }
#pragma unroll
    for (int mt = 0; mt < 8; ++mt) {
      bf16x8 a = *(const bf16x8*)&wq[(mt * 16 + l15) * 128 + ks * 32 + l4 * 8];
      acc[mt][0] = __builtin_amdgcn_mfma_f32_16x16x32_bf16(a, bq[0], acc[mt][0], 0, 0, 0);
      acc[mt][1] = __builtin_amdgcn_mfma_f32_16x16x32_bf16(a, bq[1], acc[mt][1], 0, 0, 0);
    }
  }

  // ---- atten = sum_m q*k, k = f2*ekc built in C/D layout ----
  float dp[2] = {0.f, 0.f};
#pragma unroll
  for (int mt = 0; mt < 8; ++mt) {
    int c0 = mt * 16 + l4 * 4;
#pragma unroll
    for (int nt = 0; nt < 2; ++nt) {
      int row = w * 32 + nt * 16 + l15;
      ushort4 fv = *(const ushort4*)&bufB[row * 128 + (c0 ^ swl)];
      const u16 fa[4] = { fv.x, fv.y, fv.z, fv.w };
#pragma unroll
      for (int r = 0; r < 4; ++r) {
        const float* ew = &encS[(1 * 128 + c0 + r) * 5];
        float ek = leaky(ew[0] * r0[nt] + ew[1] * r1[nt] + ew[2] * r2[nt] + ew[3]);
        dp[nt] += acc[mt][nt][r] * (bf2f(fa[r]) * ek);
      }
    }
  }
  dp[0] += __shfl_xor(dp[0], 16); dp[0] += __shfl_xor(dp[0], 32);
  dp[1] += __shfl_xor(dp[1], 16); dp[1] += __shfl_xor(dp[1], 32);

  // softmax over the 16 samples (16-lane groups)
  float aw[2];
#pragma unroll
  for (int nt = 0; nt < 2; ++nt) {
    float x = dp[nt] * 0.08838834764831845f;
    float m = x;
#pragma unroll
    for (int o = 1; o < 16; o <<= 1) m = fmaxf(m, __shfl_xor(m, o));
    float e = __expf(x - m);
    float s = e;
#pragma unroll
    for (int o = 1; o < 16; o <<= 1) s += __shfl_xor(s, o);
    aw[nt] = e / s;
  }

  // ---- v = Wv @ (f2 * ev1c) ----
  f32x4 acc2[8][2];
#pragma unroll
  for (int mt = 0; mt < 8; ++mt)
#pragma unroll
    for (int nt = 0; nt < 2; ++nt)
      acc2[mt][nt] = (f32x4){0.f, 0.f, 0.f, 0.f};

#pragma unroll
  for (int ks = 0; ks < 4; ++ks) {
    bf16x8 bv[2];
#pragma unroll
    for (int nt = 0; nt < 2; ++nt) {
      int row = w * 32 + nt * 16 + l15;
      int c0 = ks * 32 + l4 * 8;
      bf16x8 fv = *(const bf16x8*)&bufB[row * 128 + (c0 ^ swl)];
#pragma unroll
      for (int j = 0; j < 8; ++j) {
        int c = c0 + j;
        const float* ew = &encS[(2 * 128 + c) * 5];
        float e1 = leaky(ew[0] * r0[nt] + ew[1] * r1[nt] + ew[2] * r2[nt] + ew[3]);
        bv[nt][j] = (short)f2bf(bf2f((u16)fv[j]) * e1);
      }
    }
#pragma unroll
    for (int mt = 0; mt < 8; ++mt) {
      bf16x8 a = *(const bf16x8*)&wvm[(mt * 16 + l15) * 128 + ks * 32 + l4 * 8];
      acc2[mt][0] = __builtin_amdgcn_mfma_f32_16x16x32_bf16(a, bv[0], acc2[mt][0], 0, 0, 0);
      acc2[mt][1] = __builtin_amdgcn_mfma_f32_16x16x32_bf16(a, bv[1], acc2[mt][1], 0, 0, 0);
    }
  }

  // ---- out[m] = sum_s (v * ev2c * atten) + f1 ----
#pragma unroll
  for (int mt = 0; mt < 8; ++mt) {
    int m0 = mt * 16 + l4 * 4;
#pragma unroll
    for (int nt = 0; nt < 2; ++nt) {
      float s0, s1, s2, s3;
      {
        const float* e0 = &encS[(3 * 128 + m0 + 0) * 5];
        const float* e1 = &encS[(3 * 128 + m0 + 1) * 5];
        const float* e2 = &encS[(3 * 128 + m0 + 2) * 5];
        const float* e3 = &encS[(3 * 128 + m0 + 3) * 5];
        float v0 = leaky(e0[0] * r0[nt] + e0[1] * r1[nt] + e0[2] * r2[nt] + e0[3]);
        float v1 = leaky(e1[0] * r0[nt] + e1[1] * r1[nt] + e1[2] * r2[nt] + e1[3]);
        float v2 = leaky(e2[0] * r0[nt] + e2[1] * r1[nt] + e2[2] * r2[nt] + e2[3]);
        float v3 = leaky(e3[0] * r0[nt] + e3[1] * r1[nt] + e3[2] * r2[nt] + e3[3]);
        s0 = acc2[mt][nt][0] * v0 * aw[nt];
        s1 = acc2[mt][nt][1] * v1 * aw[nt];
        s2 = acc2[mt][nt][2] * v2 * aw[nt];
        s3 = acc2[mt][nt][3] * v3 * aw[nt];
      }
#pragma unroll
      for (int o = 1; o < 16; o <<= 1) {
        s0 += __shfl_xor(s0, o); s1 += __shfl_xor(s1, o);
        s2 += __shfl_xor(s2, o); s3 += __shfl_xor(s3, o);
      }
      if (l15 == 0) {
        int pt = base8 + w * 2 + nt;
        const float4 f1v = *(const float4*)&f1s[(w * 2 + nt) * 132 + m0];
        float4 ov = { s0 + f1v.x, s1 + f1v.y, s2 + f1v.z, s3 + f1v.w };
        *(float4*)&outp[(size_t)(b * NN1 + pt) * 128 + m0] = ov;
      }
    }
  }
}

// ---------------------------------------------------------------------------
// FF: h[b][d][n] = ff_w[d,:].feat_new[b][n][:] + ff_b[d]; accumulate GN stats.
__global__ __launch_bounds__(256)
void k_ff(const float* __restrict__ xin, const float* __restrict__ ffw,
          const float* __restrict__ ffb, float* __restrict__ hout,
          float* __restrict__ stats) {
  int t = threadIdx.x, bx = blockIdx.x;
  int b = bx / (NN1 / 32), n0 = (bx % (NN1 / 32)) * 32;
  __shared__ float XT[128][34];
  for (int e = t; e < 4096; e += 256) {
    int c = e & 127, nn = e >> 7;
    XT[c][nn] = xin[(b * NN1 + n0 + nn) * 128 + c];
  }
  __syncthreads();
  int d = t >> 1, nh = t & 1;
  float acc[16];
#pragma unroll
  for (int j = 0; j < 16; ++j) acc[j] = 0.0f;
  for (int c0 = 0; c0 < 128; c0 += 4) {
    float4 w4 = *(const float4*)&ffw[d * 128 + c0];
    const float wa[4] = { w4.x, w4.y, w4.z, w4.w };
#pragma unroll
    for (int k = 0; k < 4; ++k) {
      int c = c0 + k;
#pragma unroll
      for (int j2 = 0; j2 < 8; ++j2) {
        float2 xv = *(const float2*)&XT[c][nh * 16 + j2 * 2];
        acc[j2 * 2 + 0] += wa[k] * xv.x;
        acc[j2 * 2 + 1] += wa[k] * xv.y;
      }
    }
  }
  float bias = ffb[d];
  float ls = 0.0f, lss = 0.0f;
  float out[16];
#pragma unroll
  for (int j = 0; j < 16; ++j) { float h = acc[j] + bias; out[j] = h; ls += h; lss += h * h; }
#pragma unroll
  for (int j4 = 0; j4 < 4; ++j4) {
    float4 o = { out[j4 * 4], out[j4 * 4 + 1], out[j4 * 4 + 2], out[j4 * 4 + 3] };
    *(float4*)&hout[(b * 128 + d) * NN1 + n0 + nh * 16 + j4 * 4] = o;
  }
#pragma unroll
  for (int o = 1; o <= 16; o <<= 1) { ls += __shfl_xor(ls, o); lss += __shfl_xor(lss, o); }
  if ((t & 31) == 0) {
    int g = d >> 4;
    atomicAdd(&stats[(b * 8 + g) * 2 + 0], ls);
    atomicAdd(&stats[(b * 8 + g) * 2 + 1], lss);
  }
}

// Final GN + leaky + f32 store (output part 1: feat_new [B][COUT][N1]).
__global__ __launch_bounds__(256)
void k_final(const float* __restrict__ h, const float* __restrict__ stats,
             const float* __restrict__ g, const float* __restrict__ bt,
             float* __restrict__ out) {
  int e = blockIdx.x * 256 + threadIdx.x;     // < BB*128*NN1 = 2097152
  int d = (e / NN1) & 127;
  int b = e / (128 * NN1);
  int gi = (b * 8 + (d >> 4)) * 2;
  float cnt = 16.0f * (float)NN1;
  float mu = stats[gi] / cnt;
  float var = stats[gi + 1] / cnt - mu * mu;
  float rs = rsqrtf(var + 1e-5f);
  float x = (h[e] - mu) * rs * g[d] + bt[d];
  out[BB * 3 * NN1 + e] = leaky(x);
}

// ---------------------------------------------------------------------------
extern "C" void kernel_launch(void* const* d_in, const int* in_sizes, int n_in,
                              void* d_out, int out_size, void* d_ws, size_t ws_size,
                              hipStream_t stream) {
  const float* xyz1   = (const float*)d_in[0];
  const float* xyz2   = (const float*)d_in[1];
  const float* feat1  = (const float*)d_in[2];
  const float* feat2  = (const float*)d_in[3];
  const float* pos_w  = (const float*)d_in[4];
  const float* pos_b  = (const float*)d_in[5];
  const float* pos_g  = (const float*)d_in[6];
  const float* pos_bt = (const float*)d_in[7];
  const float* ek_w   = (const float*)d_in[8];
  const float* ek_b   = (const float*)d_in[9];
  const float* eq_w   = (const float*)d_in[10];
  const float* eq_b   = (const float*)d_in[11];
  const float* ev1_w  = (const float*)d_in[12];
  const float* ev1_b  = (const float*)d_in[13];
  const float* ev2_w  = (const float*)d_in[14];
  const float* ev2_b  = (const float*)d_in[15];
  const float* qk_w   = (const float*)d_in[16];
  const float* v_w    = (const float*)d_in[17];
  const float* ff_w   = (const float*)d_in[18];
  const float* ff_b   = (const float*)d_in[19];
  const float* ff_g   = (const float*)d_in[20];
  const float* ff_bt  = (const float*)d_in[21];
  (void)in_sizes; (void)n_in; (void)out_size; (void)ws_size;

  char* ws = (char*)d_ws;          // ~29.6 MB used
  float* feat1p   = (float*)(ws);                         // [B][N1][C] f32   8388608 B
  u16*   feat2pb  = (u16*)  (ws + 8388608);               // [B][N2][C] bf16  4194304 B
  float* attn_out = (float*)(ws + 12582912);              // h1 temp / knn_tmp / feat_new
  float* h_ff     = (float*)(ws + 20971520);              // h2 temp / knn_tmp / FF out
  u32*   knn_tmp  = (u32*)  (ws + 12582912);              // [B][N1][16][16] u32 = 16 MiB
  int*   idxb     = (int*)  (ws + 29360128);              // [B][N1][16]      1048576 B
  u16*   wqk      = (u16*)  (ws + 30408704);              // bf16 qk_w        32768 B
  u16*   wv       = (u16*)  (ws + 30441472);              // bf16 v_w         32768 B
  float* stats    = (float*)(ws + 30474240);              // 96 floats (384 B)
  float4* px1     = (float4*)(ws + 30474624);             // [B][N1] packed   262144 B
  float4* px2     = (float4*)(ws + 30736768);             // [B][N2] packed   262144 B

  hipMemsetAsync(stats, 0, 96 * sizeof(float), stream);
  k_w2bf<<<128, 256, 0, stream>>>(qk_w, v_w, wqk, wv);
  k_pack<<<64, 256, 0, stream>>>(xyz1, px1, NN1);
  k_pack<<<64, 256, 0, stream>>>(xyz2, px2, NN2);
  k_posenc1<<<1024, 256, 0, stream>>>(xyz1, pos_w, pos_b, attn_out, stats + 0,  NN1);
  k_posenc1<<<1024, 256, 0, stream>>>(xyz2, pos_w, pos_b, h_ff,     stats + 32, NN2);
  k_posenc2<<<1024, 256, 0, stream>>>(attn_out, feat1, pos_g, pos_bt, stats + 0,
                                      feat1p, (u16*)nullptr, NN1, 0);
  k_posenc2<<<1024, 256, 0, stream>>>(h_ff,     feat2, pos_g, pos_bt, stats + 32,
                                      (float*)nullptr, feat2pb, NN2, 1);
  k_knn1<<<4096, 64, 0, stream>>>(px1, px2, knn_tmp);
  k_knn2<<<64, 256, 0, stream>>>(knn_tmp, idxb);
  k_attn<<<2048, 256, 0, stream>>>(xyz1, xyz2, feat1p, feat2pb, idxb, wqk, wv,
                                   eq_w, eq_b, ek_w, ek_b, ev1_w, ev1_b, ev2_w, ev2_b,
                                   attn_out);
  k_ff<<<512, 256, 0, stream>>>(attn_out, ff_w, ff_b, h_ff, stats + 64);
  hipMemcpyAsync(d_out, xyz1, (size_t)(BB * 3 * NN1) * sizeof(float),
                 hipMemcpyDeviceToDevice, stream);
  k_final<<<8192, 256, 0, stream>>>(h_ff, stats + 64, ff_g, ff_bt, (float*)d_out);
}

// Round 5
// 408.853 us; speedup vs baseline: 3.3852x; 1.1578x over previous
//
#include <hip/hip_runtime.h>
#include <hip/hip_bf16.h>

// Problem constants (reference: B,N1,N2,C,COUT,NS = 2,8192,8192,128,128,16)
#define BB  2
#define NN1 8192
#define NN2 8192
#define CC  128
#define SS  16

typedef unsigned short u16;
typedef unsigned int u32;
typedef short bf16x8 __attribute__((ext_vector_type(8)));
typedef float f32x4  __attribute__((ext_vector_type(4)));

__device__ __forceinline__ u16 f2bf(float f) {
  __hip_bfloat16 h = __float2bfloat16(f);      // RNE
  return *(u16*)&h;
}
__device__ __forceinline__ float bf2f(u16 u) {
  union { float f; unsigned int u; } v; v.u = ((unsigned int)u) << 16;
  return v.f;
}
__device__ __forceinline__ float bflo(u32 w) {   // low bf16 of a dword
  union { float f; unsigned int u; } v; v.u = w << 16; return v.f;
}
__device__ __forceinline__ float bfhi(u32 w) {   // high bf16 of a dword
  union { float f; unsigned int u; } v; v.u = w & 0xFFFF0000u; return v.f;
}
__device__ __forceinline__ float leaky(float x) { return x >= 0.0f ? x : 0.1f * x; }

// ---------------------------------------------------------------------------
// prep: zero stats + convert qk_w/v_w to bf16 + pack xyz -> float4{x,y,z,|p|2}
__global__ __launch_bounds__(256)
void k_prep(const float* __restrict__ qkw, const float* __restrict__ vw,
            u16* __restrict__ oa, u16* __restrict__ ob,
            const float* __restrict__ xyz1, const float* __restrict__ xyz2,
            float4* __restrict__ px1, float4* __restrict__ px2,
            float* __restrict__ stats) {
  int bx = blockIdx.x, t = threadIdx.x;
  if (bx < 128) {
    int e = bx * 256 + t;
    if (e < 16384) oa[e] = f2bf(qkw[e]);
    else ob[e - 16384] = f2bf(vw[e - 16384]);
  } else if (bx < 192) {
    int e = (bx - 128) * 256 + t;           // < BB*NN1
    int b = e / NN1, n = e % NN1;
    float x = xyz1[(b * 3 + 0) * NN1 + n];
    float y = xyz1[(b * 3 + 1) * NN1 + n];
    float z = xyz1[(b * 3 + 2) * NN1 + n];
    px1[e] = make_float4(x, y, z, x * x + y * y + z * z);
  } else if (bx < 256) {
    int e = (bx - 192) * 256 + t;
    int b = e / NN2, n = e % NN2;
    float x = xyz2[(b * 3 + 0) * NN2 + n];
    float y = xyz2[(b * 3 + 1) * NN2 + n];
    float z = xyz2[(b * 3 + 2) * NN2 + n];
    px2[e] = make_float4(x, y, z, x * x + y * y + z * z);
  } else {
    if (t < 96) stats[t] = 0.0f;
  }
}

// ---------------------------------------------------------------------------
// pos-enc stage 1 (both clouds in one launch): h[b][n][c], accumulate stats.
__global__ __launch_bounds__(256)
void k_posenc1b(const float* __restrict__ xyz1, const float* __restrict__ xyz2,
                const float* __restrict__ pw, const float* __restrict__ pb,
                float* __restrict__ h1, float* __restrict__ h2,
                float* __restrict__ statsall) {
  int t = threadIdx.x, bx = blockIdx.x;
  const float* xyz; float* h; float* stats;
  if (bx < 1024) { xyz = xyz1; h = h1; stats = statsall; }
  else { xyz = xyz2; h = h2; stats = statsall + 32; bx -= 1024; }
  const int N = 8192;
  int b = bx / 512, n0 = (bx % 512) * 16;
  int c = t & 127, p = t >> 7;
  float w0 = pw[c * 3], w1 = pw[c * 3 + 1], w2 = pw[c * 3 + 2], bb = pb[c];
  float ls = 0.0f, lss = 0.0f;
  for (int i = 0; i < 8; ++i) {
    int n = n0 + i * 2 + p;
    float x0 = xyz[(b * 3 + 0) * N + n];
    float x1 = xyz[(b * 3 + 1) * N + n];
    float x2 = xyz[(b * 3 + 2) * N + n];
    float hv = w0 * x0 + w1 * x1 + w2 * x2 + bb;
    h[(b * N + n) * 128 + c] = hv;
    ls += hv; lss += hv * hv;
  }
#pragma unroll
  for (int o = 1; o < 16; o <<= 1) { ls += __shfl_xor(ls, o); lss += __shfl_xor(lss, o); }
  if ((t & 15) == 0) {
    int g = c >> 4;
    atomicAdd(&stats[(b * 8 + g) * 2 + 0], ls);
    atomicAdd(&stats[(b * 8 + g) * 2 + 1], lss);
  }
}

// pos-enc stage 2 (both): featp = feat + leaky(GN(h)); cloud1 f32, cloud2 bf16.
__global__ __launch_bounds__(256)
void k_posenc2b(const float* __restrict__ h1, const float* __restrict__ h2,
                const float* __restrict__ feat1, const float* __restrict__ feat2,
                const float* __restrict__ gam, const float* __restrict__ bet,
                const float* __restrict__ statsall, float* __restrict__ outf,
                u16* __restrict__ outb) {
  int t = threadIdx.x, bx = blockIdx.x;
  const float* h; const float* feat; const float* stats; int asbf;
  if (bx < 1024) { h = h1; feat = feat1; stats = statsall; asbf = 0; }
  else { h = h2; feat = feat2; stats = statsall + 32; asbf = 1; bx -= 1024; }
  const int N = 8192;
  int b = bx / 512, n0 = (bx % 512) * 16;
  __shared__ float T[128][17];
  for (int it = 0; it < 8; ++it) {
    int j = t & 15, c = it * 16 + (t >> 4);
    T[c][j] = feat[(b * 128 + c) * N + n0 + j];
  }
  __syncthreads();
  float cnt = 16.0f * (float)N;
  for (int it = 0; it < 8; ++it) {
    int c = t & 127, j = it * 2 + (t >> 7);
    float hv = h[(b * N + n0 + j) * 128 + c];
    int gi = (b * 8 + (c >> 4)) * 2;
    float mu = stats[gi] / cnt;
    float var = stats[gi + 1] / cnt - mu * mu;
    float rs = rsqrtf(var + 1e-5f);
    float x = (hv - mu) * rs * gam[c] + bet[c];
    float r = T[c][j] + leaky(x);
    if (asbf) outb[(b * N + n0 + j) * 128 + c] = f2bf(r);
    else      outf[(b * N + n0 + j) * 128 + c] = r;
  }
}

// ---------------------------------------------------------------------------
// KNN. Packed key: (f32 distance^2 bits & 0xFFFFE000) | index (13 bits).

__device__ __forceinline__ void sort16(u32 (&e)[16]) {
#pragma unroll
  for (int k = 2; k <= 16; k <<= 1) {
#pragma unroll
    for (int j = k >> 1; j > 0; j >>= 1) {
#pragma unroll
      for (int i = 0; i < 16; ++i) {
        int l = i ^ j;
        if (l > i) {
          bool up = ((i & k) == 0);
          u32 x = e[i], y = e[l];
          u32 mn = x < y ? x : y;
          u32 mx = x < y ? y : x;
          e[i] = up ? mn : mx;
          e[l] = up ? mx : mn;
        }
      }
    }
  }
}

__device__ __forceinline__ void merge16(u32 (&A)[16], const u32 (&S)[16]) {
  u32 t[16];
#pragma unroll
  for (int i = 0; i < 16; ++i) {
    u32 a = A[i], s = S[15 - i];
    t[i] = a < s ? a : s;
  }
#pragma unroll
  for (int j = 8; j > 0; j >>= 1) {
#pragma unroll
    for (int i = 0; i < 16; ++i) {
      if ((i & j) == 0) {
        u32 x = t[i], y = t[i | j];
        t[i] = x < y ? x : y;
        t[i | j] = x < y ? y : x;
      }
    }
  }
#pragma unroll
  for (int i = 0; i < 16; ++i) A[i] = t[i];
}

// Stage 1: 4 waves/block, wave = one 512-candidate slice, lane = query.
__global__ __launch_bounds__(256)
void k_knn1(const float4* __restrict__ px1, const float4* __restrict__ px2,
            u32* __restrict__ out) {
  int bx = blockIdx.x;                  // 1024 = b(2) * g(128) * sb(4)
  int w = threadIdx.x >> 6, l = threadIdx.x & 63;
  int sb = bx & 3, g = (bx >> 2) & 127, b = bx >> 9;
  int slice = sb * 4 + w;
  int q = g * 64 + l;
  float4 qv = px1[b * NN1 + q];
  u32 A[16];
#pragma unroll
  for (int i = 0; i < 16; ++i) A[i] = 0xFFFFFFFFu;
  const float4* cp = px2 + b * NN2 + slice * 512;
  for (int it = 0; it < 32; ++it) {
    u32 S[16];
#pragma unroll
    for (int kk = 0; kk < 16; ++kk) {
      float4 c = cp[it * 16 + kk];      // uniform -> scalar load
      float m = fmaf(qv.x, c.x, fmaf(qv.y, c.y, qv.z * c.z));
      float d = fmaf(-2.0f, m, qv.w + c.w);
      d = fmaxf(d, 0.0f);
      S[kk] = (__float_as_uint(d) & 0xFFFFE000u) |
              (u32)(slice * 512 + it * 16 + kk);
    }
    sort16(S);
    merge16(A, S);
  }
  u32* op = out + ((b * NN1 + q) * 16 + slice) * 16;
#pragma unroll
  for (int i = 0; i < 4; ++i)
    *(uint4*)&op[i * 4] = make_uint4(A[i * 4], A[i * 4 + 1], A[i * 4 + 2], A[i * 4 + 3]);
}

// Stage 2: one thread per query merges 16 sorted lists -> indices.
__global__ __launch_bounds__(256)
void k_knn2(const u32* __restrict__ in, int* __restrict__ idxout) {
  int e = blockIdx.x * 256 + threadIdx.x;
  const u32* p = in + (size_t)e * 256;
  u32 A[16];
#pragma unroll
  for (int i = 0; i < 4; ++i) {
    uint4 v = *(const uint4*)&p[i * 4];
    A[i * 4] = v.x; A[i * 4 + 1] = v.y; A[i * 4 + 2] = v.z; A[i * 4 + 3] = v.w;
  }
  for (int s = 1; s < 16; ++s) {
    u32 S[16];
#pragma unroll
    for (int i = 0; i < 4; ++i) {
      uint4 v = *(const uint4*)&p[s * 16 + i * 4];
      S[i * 4] = v.x; S[i * 4 + 1] = v.y; S[i * 4 + 2] = v.z; S[i * 4 + 3] = v.w;
    }
    merge16(A, S);
  }
  int* op = idxout + e * 16;
#pragma unroll
  for (int i = 0; i < 4; ++i) {
    int4 o = make_int4((int)(A[i * 4] & 8191u), (int)(A[i * 4 + 1] & 8191u),
                       (int)(A[i * 4 + 2] & 8191u), (int)(A[i * 4 + 3] & 8191u));
    *(int4*)&op[i * 4] = o;
  }
}

// ---------------------------------------------------------------------------
// Fused attention v3: wave-local, no f2 LDS staging. Each wave owns 2 points
// (2 MFMA column tiles of 16 samples), full M=128. f2 read directly from
// global (L2/L3-resident) in both layouts; encoder params + f1 in small LDS.
// encS layout: float4 slot for (enc e, channel c) at word c*16 + (e^((c>>3)&3))*4.
__device__ __forceinline__ float4 ld_enc(const float* encS, int e, int c) {
  int xe = e ^ ((c >> 3) & 3);
  return *(const float4*)&encS[c * 16 + xe * 4];
}

__global__ __launch_bounds__(256, 4)
void k_attn(const float* __restrict__ xyz1, const float* __restrict__ xyz2,
            const float* __restrict__ f1p, const u16* __restrict__ f2p,
            const int* __restrict__ idxb,
            const u16* __restrict__ wq, const u16* __restrict__ wvm,
            const float* __restrict__ eqw, const float* __restrict__ eqb,
            const float* __restrict__ ekw, const float* __restrict__ ekb,
            const float* __restrict__ ev1w, const float* __restrict__ ev1b,
            const float* __restrict__ ev2w, const float* __restrict__ ev2b,
            float* __restrict__ outp) {
  const int t = threadIdx.x, bx = blockIdx.x;
  const int b = bx >> 10;              // 1024 blocks per batch
  const int base8 = (bx & 1023) * 8;   // 8 points per block (2 per wave)
  const int w = t >> 6, l = t & 63, l15 = l & 15, l4 = l >> 4;

  __shared__ float encS[128 * 16];     // 8 KB, XOR-interleaved
  __shared__ float f1s[8 * 132];       // 4.2 KB

  // stage encoder params + f1 rows
  for (int i = t; i < 512; i += 256) {
    int e = i >> 7, c = i & 127;
    const float* wsrc = (e == 0) ? eqw : (e == 1) ? ekw : (e == 2) ? ev1w : ev2w;
    const float* bsrc = (e == 0) ? eqb : (e == 1) ? ekb : (e == 2) ? ev1b : ev2b;
    int xe = e ^ ((c >> 3) & 3);
    float* dst = &encS[c * 16 + xe * 4];
    dst[0] = wsrc[c * 3]; dst[1] = wsrc[c * 3 + 1];
    dst[2] = wsrc[c * 3 + 2]; dst[3] = bsrc[c];
  }
  for (int i = t; i < 1024; i += 256) {
    int p = i >> 7, c = i & 127;
    f1s[p * 132 + c] = f1p[(size_t)(b * NN1 + base8 + p) * 128 + c];
  }

  // per-lane neighbor indices + relative coords (sample = l15)
  const int pt0 = base8 + w * 2, pt1 = pt0 + 1;
  const int j0 = idxb[(b * NN1 + pt0) * 16 + l15];
  const int j1 = idxb[(b * NN1 + pt1) * 16 + l15];
  float r0[2], r1[2], r2[2];
  r0[0] = xyz2[(b * 3 + 0) * NN2 + j0] - xyz1[(b * 3 + 0) * NN1 + pt0];
  r1[0] = xyz2[(b * 3 + 1) * NN2 + j0] - xyz1[(b * 3 + 1) * NN1 + pt0];
  r2[0] = xyz2[(b * 3 + 2) * NN2 + j0] - xyz1[(b * 3 + 2) * NN1 + pt0];
  r0[1] = xyz2[(b * 3 + 0) * NN2 + j1] - xyz1[(b * 3 + 0) * NN1 + pt1];
  r1[1] = xyz2[(b * 3 + 1) * NN2 + j1] - xyz1[(b * 3 + 1) * NN1 + pt1];
  r2[1] = xyz2[(b * 3 + 2) * NN2 + j1] - xyz1[(b * 3 + 2) * NN1 + pt1];

  const u16* row0 = f2p + (size_t)(b * NN2 + j0) * 128;
  const u16* row1 = f2p + (size_t)(b * NN2 + j1) * 128;

  // attention-dot-path gather: f2[row][mt*16 + l4*4 + 0..3] as 2 dwords
  uint2 kd0[8], kd1[8];
#pragma unroll
  for (int mt = 0; mt < 8; ++mt) {
    kd0[mt] = *(const uint2*)(row0 + mt * 16 + l4 * 4);
    kd1[mt] = *(const uint2*)(row1 + mt * 16 + l4 * 4);
  }
  __syncthreads();

  // ---- build bq fragments: qin = f1 * leaky(eq.r + b), B-layout ----
  bf16x8 bq[2][4];
#pragma unroll
  for (int ks = 0; ks < 4; ++ks) {
#pragma unroll
    for (int j = 0; j < 8; ++j) {
      int c = ks * 32 + l4 * 8 + j;
      float4 ew = ld_enc(encS, 0, c);
      float f10 = f1s[(w * 2 + 0) * 132 + c];
      float f11 = f1s[(w * 2 + 1) * 132 + c];
      float e0 = leaky(ew.x * r0[0] + ew.y * r1[0] + ew.z * r2[0] + ew.w);
      float e1 = leaky(ew.x * r0[1] + ew.y * r1[1] + ew.z * r2[1] + ew.w);
      bq[0][ks][j] = (short)f2bf(f10 * e0);
      bq[1][ks][j] = (short)f2bf(f11 * e1);
    }
  }

  // ---- GEMM1 (q = Wq @ qin) interleaved with attention dot per mt ----
  float dp0 = 0.0f, dp1 = 0.0f;
#pragma unroll
  for (int mt = 0; mt < 8; ++mt) {
    f32x4 a0 = (f32x4){0.f, 0.f, 0.f, 0.f};
    f32x4 a1 = (f32x4){0.f, 0.f, 0.f, 0.f};
#pragma unroll
    for (int ks = 0; ks < 4; ++ks) {
      bf16x8 af = *(const bf16x8*)&wq[(mt * 16 + l15) * 128 + ks * 32 + l4 * 8];
      a0 = __builtin_amdgcn_mfma_f32_16x16x32_bf16(af, bq[0][ks], a0, 0, 0, 0);
      a1 = __builtin_amdgcn_mfma_f32_16x16x32_bf16(af, bq[1][ks], a1, 0, 0, 0);
    }
    float f2v0[4] = { bflo(kd0[mt].x), bfhi(kd0[mt].x), bflo(kd0[mt].y), bfhi(kd0[mt].y) };
    float f2v1[4] = { bflo(kd1[mt].x), bfhi(kd1[mt].x), bflo(kd1[mt].y), bfhi(kd1[mt].y) };
#pragma unroll
    for (int r = 0; r < 4; ++r) {
      int c = mt * 16 + l4 * 4 + r;
      float4 ew = ld_enc(encS, 1, c);
      float ek0 = leaky(ew.x * r0[0] + ew.y * r1[0] + ew.z * r2[0] + ew.w);
      float ek1 = leaky(ew.x * r0[1] + ew.y * r1[1] + ew.z * r2[1] + ew.w);
      dp0 += a0[r] * (f2v0[r] * ek0);
      dp1 += a1[r] * (f2v1[r] * ek1);
    }
  }

  // V-path gather (B-layout fragments), issued before softmax to hide latency
  bf16x8 fB[2][4];
#pragma unroll
  for (int ks = 0; ks < 4; ++ks) {
    fB[0][ks] = *(const bf16x8*)(row0 + ks * 32 + l4 * 8);
    fB[1][ks] = *(const bf16x8*)(row1 + ks * 32 + l4 * 8);
  }

  // reduce dot over l4 groups, then 16-lane softmax
  dp0 += __shfl_xor(dp0, 16); dp0 += __shfl_xor(dp0, 32);
  dp1 += __shfl_xor(dp1, 16); dp1 += __shfl_xor(dp1, 32);
  float aw0, aw1;
  {
    float x = dp0 * 0.08838834764831845f;
    float m = x;
#pragma unroll
    for (int o = 1; o < 16; o <<= 1) m = fmaxf(m, __shfl_xor(m, o));
    float e = __expf(x - m);
    float s = e;
#pragma unroll
    for (int o = 1; o < 16; o <<= 1) s += __shfl_xor(s, o);
    aw0 = e / s;
  }
  {
    float x = dp1 * 0.08838834764831845f;
    float m = x;
#pragma unroll
    for (int o = 1; o < 16; o <<= 1) m = fmaxf(m, __shfl_xor(m, o));
    float e = __expf(x - m);
    float s = e;
#pragma unroll
    for (int o = 1; o < 16; o <<= 1) s += __shfl_xor(s, o);
    aw1 = e / s;
  }

  // ---- build bv fragments: vin = f2 * leaky(ev1.r + b) ----
  bf16x8 bv[2][4];
#pragma unroll
  for (int ks = 0; ks < 4; ++ks) {
#pragma unroll
    for (int j = 0; j < 8; ++j) {
      int c = ks * 32 + l4 * 8 + j;
      float4 ew = ld_enc(encS, 2, c);
      float e0 = leaky(ew.x * r0[0] + ew.y * r1[0] + ew.z * r2[0] + ew.w);
      float e1 = leaky(ew.x * r0[1] + ew.y * r1[1] + ew.z * r2[1] + ew.w);
      bv[0][ks][j] = (short)f2bf(bf2f((u16)fB[0][ks][j]) * e0);
      bv[1][ks][j] = (short)f2bf(bf2f((u16)fB[1][ks][j]) * e1);
    }
  }

  // ---- GEMM2 (v = Wv @ vin) + ev2 scale + atten-weighted reduce + store ----
#pragma unroll
  for (int mt = 0; mt < 8; ++mt) {
    f32x4 a0 = (f32x4){0.f, 0.f, 0.f, 0.f};
    f32x4 a1 = (f32x4){0.f, 0.f, 0.f, 0.f};
#pragma unroll
    for (int ks = 0; ks < 4; ++ks) {
      bf16x8 af = *(const bf16x8*)&wvm[(mt * 16 + l15) * 128 + ks * 32 + l4 * 8];
      a0 = __builtin_amdgcn_mfma_f32_16x16x32_bf16(af, bv[0][ks], a0, 0, 0, 0);
      a1 = __builtin_amdgcn_mfma_f32_16x16x32_bf16(af, bv[1][ks], a1, 0, 0, 0);
    }
    int m0 = mt * 16 + l4 * 4;
    float s0[4], s1[4];
#pragma unroll
    for (int r = 0; r < 4; ++r) {
      float4 ew = ld_enc(encS, 3, m0 + r);
      float v0 = leaky(ew.x * r0[0] + ew.y * r1[0] + ew.z * r2[0] + ew.w);
      float v1 = leaky(ew.x * r0[1] + ew.y * r1[1] + ew.z * r2[1] + ew.w);
      s0[r] = a0[r] * v0 * aw0;
      s1[r] = a1[r] * v1 * aw1;
    }
#pragma unroll
    for (int o = 1; o < 16; o <<= 1) {
      s0[0] += __shfl_xor(s0[0], o); s0[1] += __shfl_xor(s0[1], o);
      s0[2] += __shfl_xor(s0[2], o); s0[3] += __shfl_xor(s0[3], o);
      s1[0] += __shfl_xor(s1[0], o); s1[1] += __shfl_xor(s1[1], o);
      s1[2] += __shfl_xor(s1[2], o); s1[3] += __shfl_xor(s1[3], o);
    }
    if (l15 == 0) {
      const float4 f1v0 = *(const float4*)&f1s[(w * 2 + 0) * 132 + m0];
      const float4 f1v1 = *(const float4*)&f1s[(w * 2 + 1) * 132 + m0];
      float4 o0 = { s0[0] + f1v0.x, s0[1] + f1v0.y, s0[2] + f1v0.z, s0[3] + f1v0.w };
      float4 o1 = { s1[0] + f1v1.x, s1[1] + f1v1.y, s1[2] + f1v1.z, s1[3] + f1v1.w };
      *(float4*)&outp[(size_t)(b * NN1 + pt0) * 128 + m0] = o0;
      *(float4*)&outp[(size_t)(b * NN1 + pt1) * 128 + m0] = o1;
    }
  }
}

// ---------------------------------------------------------------------------
// FF: h[b][d][n] = ff_w[d,:].feat_new[b][n][:] + ff_b[d]; accumulate GN stats.
__global__ __launch_bounds__(256)
void k_ff(const float* __restrict__ xin, const float* __restrict__ ffw,
          const float* __restrict__ ffb, float* __restrict__ hout,
          float* __restrict__ stats) {
  int t = threadIdx.x, bx = blockIdx.x;
  int b = bx / (NN1 / 32), n0 = (bx % (NN1 / 32)) * 32;
  __shared__ float XT[128][34];
  for (int e = t; e < 4096; e += 256) {
    int c = e & 127, nn = e >> 7;
    XT[c][nn] = xin[(b * NN1 + n0 + nn) * 128 + c];
  }
  __syncthreads();
  int d = t >> 1, nh = t & 1;
  float acc[16];
#pragma unroll
  for (int j = 0; j < 16; ++j) acc[j] = 0.0f;
  for (int c0 = 0; c0 < 128; c0 += 4) {
    float4 w4 = *(const float4*)&ffw[d * 128 + c0];
    const float wa[4] = { w4.x, w4.y, w4.z, w4.w };
#pragma unroll
    for (int k = 0; k < 4; ++k) {
      int c = c0 + k;
#pragma unroll
      for (int j2 = 0; j2 < 8; ++j2) {
        float2 xv = *(const float2*)&XT[c][nh * 16 + j2 * 2];
        acc[j2 * 2 + 0] += wa[k] * xv.x;
        acc[j2 * 2 + 1] += wa[k] * xv.y;
      }
    }
  }
  float bias = ffb[d];
  float ls = 0.0f, lss = 0.0f;
  float out[16];
#pragma unroll
  for (int j = 0; j < 16; ++j) { float h = acc[j] + bias; out[j] = h; ls += h; lss += h * h; }
#pragma unroll
  for (int j4 = 0; j4 < 4; ++j4) {
    float4 o = { out[j4 * 4], out[j4 * 4 + 1], out[j4 * 4 + 2], out[j4 * 4 + 3] };
    *(float4*)&hout[(b * 128 + d) * NN1 + n0 + nh * 16 + j4 * 4] = o;
  }
#pragma unroll
  for (int o = 1; o <= 16; o <<= 1) { ls += __shfl_xor(ls, o); lss += __shfl_xor(lss, o); }
  if ((t & 31) == 0) {
    int g = d >> 4;
    atomicAdd(&stats[(b * 8 + g) * 2 + 0], ls);
    atomicAdd(&stats[(b * 8 + g) * 2 + 1], lss);
  }
}

// Final GN + leaky + f32 store; also writes the xyz1 passthrough (blocks >= 8192).
__global__ __launch_bounds__(256)
void k_final(const float* __restrict__ h, const float* __restrict__ stats,
             const float* __restrict__ g, const float* __restrict__ bt,
             const float* __restrict__ xyz1, float* __restrict__ out) {
  int bx = blockIdx.x;
  if (bx >= 8192) {
    int e = (bx - 8192) * 256 + threadIdx.x;   // < BB*3*NN1 = 49152
    out[e] = xyz1[e];
    return;
  }
  int e = bx * 256 + threadIdx.x;              // < BB*128*NN1 = 2097152
  int d = (e / NN1) & 127;
  int b = e / (128 * NN1);
  int gi = (b * 8 + (d >> 4)) * 2;
  float cnt = 16.0f * (float)NN1;
  float mu = stats[gi] / cnt;
  float var = stats[gi + 1] / cnt - mu * mu;
  float rs = rsqrtf(var + 1e-5f);
  float x = (h[e] - mu) * rs * g[d] + bt[d];
  out[BB * 3 * NN1 + e] = leaky(x);
}

// ---------------------------------------------------------------------------
extern "C" void kernel_launch(void* const* d_in, const int* in_sizes, int n_in,
                              void* d_out, int out_size, void* d_ws, size_t ws_size,
                              hipStream_t stream) {
  const float* xyz1   = (const float*)d_in[0];
  const float* xyz2   = (const float*)d_in[1];
  const float* feat1  = (const float*)d_in[2];
  const float* feat2  = (const float*)d_in[3];
  const float* pos_w  = (const float*)d_in[4];
  const float* pos_b  = (const float*)d_in[5];
  const float* pos_g  = (const float*)d_in[6];
  const float* pos_bt = (const float*)d_in[7];
  const float* ek_w   = (const float*)d_in[8];
  const float* ek_b   = (const float*)d_in[9];
  const float* eq_w   = (const float*)d_in[10];
  const float* eq_b   = (const float*)d_in[11];
  const float* ev1_w  = (const float*)d_in[12];
  const float* ev1_b  = (const float*)d_in[13];
  const float* ev2_w  = (const float*)d_in[14];
  const float* ev2_b  = (const float*)d_in[15];
  const float* qk_w   = (const float*)d_in[16];
  const float* v_w    = (const float*)d_in[17];
  const float* ff_w   = (const float*)d_in[18];
  const float* ff_b   = (const float*)d_in[19];
  const float* ff_g   = (const float*)d_in[20];
  const float* ff_bt  = (const float*)d_in[21];
  (void)in_sizes; (void)n_in; (void)out_size; (void)ws_size;

  char* ws = (char*)d_ws;          // ~31 MB used
  float* feat1p   = (float*)(ws);                         // [B][N1][C] f32   8388608 B
  u16*   feat2pb  = (u16*)  (ws + 8388608);               // [B][N2][C] bf16  4194304 B
  float* attn_out = (float*)(ws + 12582912);              // h1 temp / knn_tmp / feat_new
  float* h_ff     = (float*)(ws + 20971520);              // h2 temp / knn_tmp / FF out
  u32*   knn_tmp  = (u32*)  (ws + 12582912);              // [B][N1][16][16] u32 = 16 MiB
  int*   idxb     = (int*)  (ws + 29360128);              // [B][N1][16]      1048576 B
  u16*   wqk      = (u16*)  (ws + 30408704);              // bf16 qk_w        32768 B
  u16*   wv       = (u16*)  (ws + 30441472);              // bf16 v_w         32768 B
  float* stats    = (float*)(ws + 30474240);              // 96 floats (384 B)
  float4* px1     = (float4*)(ws + 30474624);             // [B][N1] packed   262144 B
  float4* px2     = (float4*)(ws + 30736768);             // [B][N2] packed   262144 B

  k_prep<<<257, 256, 0, stream>>>(qk_w, v_w, wqk, wv, xyz1, xyz2, px1, px2, stats);
  k_posenc1b<<<2048, 256, 0, stream>>>(xyz1, xyz2, pos_w, pos_b, attn_out, h_ff, stats);
  k_posenc2b<<<2048, 256, 0, stream>>>(attn_out, h_ff, feat1, feat2, pos_g, pos_bt,
                                       stats, feat1p, feat2pb);
  k_knn1<<<1024, 256, 0, stream>>>(px1, px2, knn_tmp);
  k_knn2<<<64, 256, 0, stream>>>(knn_tmp, idxb);
  k_attn<<<2048, 256, 0, stream>>>(xyz1, xyz2, feat1p, feat2pb, idxb, wqk, wv,
                                   eq_w, eq_b, ek_w, ek_b, ev1_w, ev1_b, ev2_w, ev2_b,
                                   attn_out);
  k_ff<<<512, 256, 0, stream>>>(attn_out, ff_w, ff_b, h_ff, stats + 64);
  k_final<<<8384, 256, 0, stream>>>(h_ff, stats + 64, ff_g, ff_bt, xyz1, (float*)d_out);
}

// Round 6
// 272.193 us; speedup vs baseline: 5.0848x; 1.5021x over previous
//
#include <hip/hip_runtime.h>
#include <hip/hip_bf16.h>

// Problem constants (reference: B,N1,N2,C,COUT,NS = 2,8192,8192,128,128,16)
#define BB  2
#define NN1 8192
#define NN2 8192
#define CC  128
#define SS  16

typedef unsigned short u16;
typedef unsigned int u32;
typedef short bf16x8 __attribute__((ext_vector_type(8)));
typedef float f32x4  __attribute__((ext_vector_type(4)));

__device__ __forceinline__ u16 f2bf(float f) {
  __hip_bfloat16 h = __float2bfloat16(f);      // RNE
  return *(u16*)&h;
}
__device__ __forceinline__ float bf2f(u16 u) {
  union { float f; unsigned int u; } v; v.u = ((unsigned int)u) << 16;
  return v.f;
}
__device__ __forceinline__ float bflo(u32 w) {
  union { float f; unsigned int u; } v; v.u = w << 16; return v.f;
}
__device__ __forceinline__ float bfhi(u32 w) {
  union { float f; unsigned int u; } v; v.u = w & 0xFFFF0000u; return v.f;
}
__device__ __forceinline__ float leaky(float x) { return x >= 0.0f ? x : 0.1f * x; }

// ---------------------------------------------------------------------------
// prep: convert qk_w/v_w to bf16; pack xyz -> float4{x,y,z,|p|2}; accumulate
// per-(cloud,batch) xyz moments (9 sums) for analytic GroupNorm stats.
__global__ __launch_bounds__(256)
void k_prep(const float* __restrict__ qkw, const float* __restrict__ vw,
            u16* __restrict__ oa, u16* __restrict__ ob,
            const float* __restrict__ xyz1, const float* __restrict__ xyz2,
            float4* __restrict__ px1, float4* __restrict__ px2,
            float* __restrict__ mom) {
  int bx = blockIdx.x, t = threadIdx.x;
  if (bx < 128) {
    int e = bx * 256 + t;
    if (e < 16384) oa[e] = f2bf(qkw[e]);
    else ob[e - 16384] = f2bf(vw[e - 16384]);
    return;
  }
  const float* xyz; float4* px; int e, cl;
  if (bx < 192) { e = (bx - 128) * 256 + t; xyz = xyz1; px = px1; cl = 0; }
  else          { e = (bx - 192) * 256 + t; xyz = xyz2; px = px2; cl = 1; }
  int b = e >> 13, n = e & 8191;
  float x = xyz[(b * 3 + 0) * 8192 + n];
  float y = xyz[(b * 3 + 1) * 8192 + n];
  float z = xyz[(b * 3 + 2) * 8192 + n];
  px[e] = make_float4(x, y, z, x * x + y * y + z * z);
  float s0 = x, s1 = y, s2 = z, s3 = x * x, s4 = y * y, s5 = z * z;
  float s6 = x * y, s7 = x * z, s8 = y * z;
#pragma unroll
  for (int o = 1; o < 64; o <<= 1) {
    s0 += __shfl_xor(s0, o); s1 += __shfl_xor(s1, o); s2 += __shfl_xor(s2, o);
    s3 += __shfl_xor(s3, o); s4 += __shfl_xor(s4, o); s5 += __shfl_xor(s5, o);
    s6 += __shfl_xor(s6, o); s7 += __shfl_xor(s7, o); s8 += __shfl_xor(s8, o);
  }
  if ((t & 63) == 0) {
    float* mp = mom + (cl * 2 + b) * 9;
    atomicAdd(&mp[0], s0); atomicAdd(&mp[1], s1); atomicAdd(&mp[2], s2);
    atomicAdd(&mp[3], s3); atomicAdd(&mp[4], s4); atomicAdd(&mp[5], s5);
    atomicAdd(&mp[6], s6); atomicAdd(&mp[7], s7); atomicAdd(&mp[8], s8);
  }
}

// Analytic GN stats: for each (cloud,b,group) compute mu and rsqrt(var+eps)
// of h = pos_w . xyz + pos_b over (16 channels x N points).
__global__ __launch_bounds__(512)
void k_gnstats(const float* __restrict__ mom, const float* __restrict__ pw,
               const float* __restrict__ pb, float2* __restrict__ gnp) {
  int t = threadIdx.x;                 // 512: cloud(2) x b(2) x c(128)
  int cl = t >> 8, b = (t >> 7) & 1, c = t & 127;
  const float* M = mom + (cl * 2 + b) * 9;
  const float inv = 1.0f / 8192.0f;
  float mx = M[0] * inv, my = M[1] * inv, mz = M[2] * inv;
  float sxx = M[3] * inv, syy = M[4] * inv, szz = M[5] * inv;
  float sxy = M[6] * inv, sxz = M[7] * inv, syz = M[8] * inv;
  float w0 = pw[c * 3], w1 = pw[c * 3 + 1], w2 = pw[c * 3 + 2], bc = pb[c];
  float wm = w0 * mx + w1 * my + w2 * mz;
  float Eh = wm + bc;
  float wSw = w0 * w0 * sxx + w1 * w1 * syy + w2 * w2 * szz
            + 2.0f * (w0 * w1 * sxy + w0 * w2 * sxz + w1 * w2 * syz);
  float Eh2 = wSw + 2.0f * bc * wm + bc * bc;
#pragma unroll
  for (int o = 1; o < 16; o <<= 1) { Eh += __shfl_xor(Eh, o); Eh2 += __shfl_xor(Eh2, o); }
  if ((c & 15) == 0) {
    float mu = Eh * 0.0625f;
    float var = Eh2 * 0.0625f - mu * mu;
    gnp[cl * 16 + b * 8 + (c >> 4)] = make_float2(mu, rsqrtf(var + 1e-5f));
  }
}

// Fused pos-enc (single pass, both clouds): featp = feat + leaky(GN(W.xyz+b)).
// cloud1 -> f32, cloud2 -> bf16.
__global__ __launch_bounds__(256)
void k_posenc(const float* __restrict__ xyz1, const float* __restrict__ xyz2,
              const float* __restrict__ feat1, const float* __restrict__ feat2,
              const float* __restrict__ pw, const float* __restrict__ pb,
              const float* __restrict__ gam, const float* __restrict__ bet,
              const float2* __restrict__ gnp,
              float* __restrict__ outf, u16* __restrict__ outb) {
  int t = threadIdx.x, bx = blockIdx.x;
  const float* xyz; const float* feat; const float2* gp; int asbf;
  if (bx < 1024) { xyz = xyz1; feat = feat1; gp = gnp;      asbf = 0; }
  else           { xyz = xyz2; feat = feat2; gp = gnp + 16; asbf = 1; bx -= 1024; }
  const int N = 8192;
  int b = bx / 512, n0 = (bx % 512) * 16;
  __shared__ float T[128][17];
  for (int it = 0; it < 8; ++it) {
    int j = t & 15, c = it * 16 + (t >> 4);
    T[c][j] = feat[(b * 128 + c) * N + n0 + j];
  }
  int c = t & 127;
  float w0 = pw[c * 3], w1 = pw[c * 3 + 1], w2 = pw[c * 3 + 2], bc = pb[c];
  float2 g2 = gp[b * 8 + (c >> 4)];
  float gm = gam[c], b2 = bet[c];
  __syncthreads();
  for (int it = 0; it < 8; ++it) {
    int j = it * 2 + (t >> 7);
    int n = n0 + j;
    float xs = xyz[(b * 3 + 0) * N + n];
    float ys = xyz[(b * 3 + 1) * N + n];
    float zs = xyz[(b * 3 + 2) * N + n];
    float hv = w0 * xs + w1 * ys + w2 * zs + bc;
    float xo = (hv - g2.x) * g2.y * gm + b2;
    float r = T[c][j] + leaky(xo);
    if (asbf) outb[(size_t)(b * N + n) * 128 + c] = f2bf(r);
    else      outf[(size_t)(b * N + n) * 128 + c] = r;
  }
}

// ---------------------------------------------------------------------------
// KNN. Packed key: (f32 distance^2 bits & 0xFFFFE000) | index (13 bits).

__device__ __forceinline__ void sort16(u32 (&e)[16]) {
#pragma unroll
  for (int k = 2; k <= 16; k <<= 1) {
#pragma unroll
    for (int j = k >> 1; j > 0; j >>= 1) {
#pragma unroll
      for (int i = 0; i < 16; ++i) {
        int l = i ^ j;
        if (l > i) {
          bool up = ((i & k) == 0);
          u32 x = e[i], y = e[l];
          u32 mn = x < y ? x : y;
          u32 mx = x < y ? y : x;
          e[i] = up ? mn : mx;
          e[l] = up ? mx : mn;
        }
      }
    }
  }
}

__device__ __forceinline__ void merge16(u32 (&A)[16], const u32 (&S)[16]) {
  u32 t[16];
#pragma unroll
  for (int i = 0; i < 16; ++i) {
    u32 a = A[i], s = S[15 - i];
    t[i] = a < s ? a : s;
  }
#pragma unroll
  for (int j = 8; j > 0; j >>= 1) {
#pragma unroll
    for (int i = 0; i < 16; ++i) {
      if ((i & j) == 0) {
        u32 x = t[i], y = t[i | j];
        t[i] = x < y ? x : y;
        t[i | j] = x < y ? y : x;
      }
    }
  }
#pragma unroll
  for (int i = 0; i < 16; ++i) A[i] = t[i];
}

// Stage 1: 4 waves/block, wave = one 512-candidate slice, lane = query.
__global__ __launch_bounds__(256)
void k_knn1(const float4* __restrict__ px1, const float4* __restrict__ px2,
            u32* __restrict__ out) {
  int bx = blockIdx.x;                  // 1024 = b(2) * g(128) * sb(4)
  int w = threadIdx.x >> 6, l = threadIdx.x & 63;
  int sb = bx & 3, g = (bx >> 2) & 127, b = bx >> 9;
  int slice = sb * 4 + w;
  int q = g * 64 + l;
  float4 qv = px1[b * NN1 + q];
  u32 A[16];
#pragma unroll
  for (int i = 0; i < 16; ++i) A[i] = 0xFFFFFFFFu;
  const float4* cp = px2 + b * NN2 + slice * 512;
  for (int it = 0; it < 32; ++it) {
    u32 S[16];
#pragma unroll
    for (int kk = 0; kk < 16; ++kk) {
      float4 c = cp[it * 16 + kk];      // uniform -> scalar load
      float m = fmaf(qv.x, c.x, fmaf(qv.y, c.y, qv.z * c.z));
      float d = fmaf(-2.0f, m, qv.w + c.w);
      d = fmaxf(d, 0.0f);
      S[kk] = (__float_as_uint(d) & 0xFFFFE000u) |
              (u32)(slice * 512 + it * 16 + kk);
    }
    sort16(S);
    merge16(A, S);
  }
  u32* op = out + ((b * NN1 + q) * 16 + slice) * 16;
#pragma unroll
  for (int i = 0; i < 4; ++i)
    *(uint4*)&op[i * 4] = make_uint4(A[i * 4], A[i * 4 + 1], A[i * 4 + 2], A[i * 4 + 3]);
}

// Stage 2: one thread per query merges 16 sorted lists -> indices.
__global__ __launch_bounds__(256)
void k_knn2(const u32* __restrict__ in, int* __restrict__ idxout) {
  int e = blockIdx.x * 256 + threadIdx.x;
  const u32* p = in + (size_t)e * 256;
  u32 A[16];
#pragma unroll
  for (int i = 0; i < 4; ++i) {
    uint4 v = *(const uint4*)&p[i * 4];
    A[i * 4] = v.x; A[i * 4 + 1] = v.y; A[i * 4 + 2] = v.z; A[i * 4 + 3] = v.w;
  }
  for (int s = 1; s < 16; ++s) {
    u32 S[16];
#pragma unroll
    for (int i = 0; i < 4; ++i) {
      uint4 v = *(const uint4*)&p[s * 16 + i * 4];
      S[i * 4] = v.x; S[i * 4 + 1] = v.y; S[i * 4 + 2] = v.z; S[i * 4 + 3] = v.w;
    }
    merge16(A, S);
  }
  int* op = idxout + e * 16;
#pragma unroll
  for (int i = 0; i < 4; ++i) {
    int4 o = make_int4((int)(A[i * 4] & 8191u), (int)(A[i * 4 + 1] & 8191u),
                       (int)(A[i * 4 + 2] & 8191u), (int)(A[i * 4 + 3] & 8191u));
    *(int4*)&op[i * 4] = o;
  }
}

// ---------------------------------------------------------------------------
// Fused attention v3: wave-local, no f2 LDS staging; encoder params + f1 in
// small LDS; f2 read directly from global (L2/L3-resident) in both layouts.
__device__ __forceinline__ float4 ld_enc(const float* encS, int e, int c) {
  int xe = e ^ ((c >> 3) & 3);
  return *(const float4*)&encS[c * 16 + xe * 4];
}

__global__ __launch_bounds__(256, 2)
void k_attn(const float* __restrict__ xyz1, const float* __restrict__ xyz2,
            const float* __restrict__ f1p, const u16* __restrict__ f2p,
            const int* __restrict__ idxb,
            const u16* __restrict__ wq, const u16* __restrict__ wvm,
            const float* __restrict__ eqw, const float* __restrict__ eqb,
            const float* __restrict__ ekw, const float* __restrict__ ekb,
            const float* __restrict__ ev1w, const float* __restrict__ ev1b,
            const float* __restrict__ ev2w, const float* __restrict__ ev2b,
            float* __restrict__ outp) {
  const int t = threadIdx.x, bx = blockIdx.x;
  const int b = bx >> 10;              // 1024 blocks per batch
  const int base8 = (bx & 1023) * 8;   // 8 points per block (2 per wave)
  const int w = t >> 6, l = t & 63, l15 = l & 15, l4 = l >> 4;

  __shared__ float encS[128 * 16];     // 8 KB, XOR-interleaved
  __shared__ float f1s[8 * 132];       // 4.2 KB

  // stage encoder params + f1 rows
  for (int i = t; i < 512; i += 256) {
    int e = i >> 7, c = i & 127;
    const float* wsrc = (e == 0) ? eqw : (e == 1) ? ekw : (e == 2) ? ev1w : ev2w;
    const float* bsrc = (e == 0) ? eqb : (e == 1) ? ekb : (e == 2) ? ev1b : ev2b;
    int xe = e ^ ((c >> 3) & 3);
    float* dst = &encS[c * 16 + xe * 4];
    dst[0] = wsrc[c * 3]; dst[1] = wsrc[c * 3 + 1];
    dst[2] = wsrc[c * 3 + 2]; dst[3] = bsrc[c];
  }
  for (int i = t; i < 1024; i += 256) {
    int p = i >> 7, c = i & 127;
    f1s[p * 132 + c] = f1p[(size_t)(b * NN1 + base8 + p) * 128 + c];
  }

  // per-lane neighbor indices + relative coords (sample = l15)
  const int pt0 = base8 + w * 2, pt1 = pt0 + 1;
  const int j0 = idxb[(b * NN1 + pt0) * 16 + l15];
  const int j1 = idxb[(b * NN1 + pt1) * 16 + l15];
  float r0[2], r1[2], r2[2];
  r0[0] = xyz2[(b * 3 + 0) * NN2 + j0] - xyz1[(b * 3 + 0) * NN1 + pt0];
  r1[0] = xyz2[(b * 3 + 1) * NN2 + j0] - xyz1[(b * 3 + 1) * NN1 + pt0];
  r2[0] = xyz2[(b * 3 + 2) * NN2 + j0] - xyz1[(b * 3 + 2) * NN1 + pt0];
  r0[1] = xyz2[(b * 3 + 0) * NN2 + j1] - xyz1[(b * 3 + 0) * NN1 + pt1];
  r1[1] = xyz2[(b * 3 + 1) * NN2 + j1] - xyz1[(b * 3 + 1) * NN1 + pt1];
  r2[1] = xyz2[(b * 3 + 2) * NN2 + j1] - xyz1[(b * 3 + 2) * NN1 + pt1];

  const u16* row0 = f2p + (size_t)(b * NN2 + j0) * 128;
  const u16* row1 = f2p + (size_t)(b * NN2 + j1) * 128;

  // attention-dot-path gather: f2[row][mt*16 + l4*4 + 0..3] as 2 dwords
  uint2 kd0[8], kd1[8];
#pragma unroll
  for (int mt = 0; mt < 8; ++mt) {
    kd0[mt] = *(const uint2*)(row0 + mt * 16 + l4 * 4);
    kd1[mt] = *(const uint2*)(row1 + mt * 16 + l4 * 4);
  }
  __syncthreads();

  // ---- build bq fragments: qin = f1 * leaky(eq.r + b), B-layout ----
  bf16x8 bq[2][4];
#pragma unroll
  for (int ks = 0; ks < 4; ++ks) {
#pragma unroll
    for (int j = 0; j < 8; ++j) {
      int c = ks * 32 + l4 * 8 + j;
      float4 ew = ld_enc(encS, 0, c);
      float f10 = f1s[(w * 2 + 0) * 132 + c];
      float f11 = f1s[(w * 2 + 1) * 132 + c];
      float e0 = leaky(ew.x * r0[0] + ew.y * r1[0] + ew.z * r2[0] + ew.w);
      float e1 = leaky(ew.x * r0[1] + ew.y * r1[1] + ew.z * r2[1] + ew.w);
      bq[0][ks][j] = (short)f2bf(f10 * e0);
      bq[1][ks][j] = (short)f2bf(f11 * e1);
    }
  }

  // ---- GEMM1 (q = Wq @ qin) interleaved with attention dot per mt ----
  float dp0 = 0.0f, dp1 = 0.0f;
#pragma unroll
  for (int mt = 0; mt < 8; ++mt) {
    f32x4 a0 = (f32x4){0.f, 0.f, 0.f, 0.f};
    f32x4 a1 = (f32x4){0.f, 0.f, 0.f, 0.f};
#pragma unroll
    for (int ks = 0; ks < 4; ++ks) {
      bf16x8 af = *(const bf16x8*)&wq[(mt * 16 + l15) * 128 + ks * 32 + l4 * 8];
      a0 = __builtin_amdgcn_mfma_f32_16x16x32_bf16(af, bq[0][ks], a0, 0, 0, 0);
      a1 = __builtin_amdgcn_mfma_f32_16x16x32_bf16(af, bq[1][ks], a1, 0, 0, 0);
    }
    float f2v0[4] = { bflo(kd0[mt].x), bfhi(kd0[mt].x), bflo(kd0[mt].y), bfhi(kd0[mt].y) };
    float f2v1[4] = { bflo(kd1[mt].x), bfhi(kd1[mt].x), bflo(kd1[mt].y), bfhi(kd1[mt].y) };
#pragma unroll
    for (int r = 0; r < 4; ++r) {
      int c = mt * 16 + l4 * 4 + r;
      float4 ew = ld_enc(encS, 1, c);
      float ek0 = leaky(ew.x * r0[0] + ew.y * r1[0] + ew.z * r2[0] + ew.w);
      float ek1 = leaky(ew.x * r0[1] + ew.y * r1[1] + ew.z * r2[1] + ew.w);
      dp0 += a0[r] * (f2v0[r] * ek0);
      dp1 += a1[r] * (f2v1[r] * ek1);
    }
  }

  // V-path gather (B-layout fragments), issued before softmax to hide latency
  bf16x8 fB[2][4];
#pragma unroll
  for (int ks = 0; ks < 4; ++ks) {
    fB[0][ks] = *(const bf16x8*)(row0 + ks * 32 + l4 * 8);
    fB[1][ks] = *(const bf16x8*)(row1 + ks * 32 + l4 * 8);
  }

  // reduce dot over l4 groups, then 16-lane softmax
  dp0 += __shfl_xor(dp0, 16); dp0 += __shfl_xor(dp0, 32);
  dp1 += __shfl_xor(dp1, 16); dp1 += __shfl_xor(dp1, 32);
  float aw0, aw1;
  {
    float x = dp0 * 0.08838834764831845f;
    float m = x;
#pragma unroll
    for (int o = 1; o < 16; o <<= 1) m = fmaxf(m, __shfl_xor(m, o));
    float e = __expf(x - m);
    float s = e;
#pragma unroll
    for (int o = 1; o < 16; o <<= 1) s += __shfl_xor(s, o);
    aw0 = e / s;
  }
  {
    float x = dp1 * 0.08838834764831845f;
    float m = x;
#pragma unroll
    for (int o = 1; o < 16; o <<= 1) m = fmaxf(m, __shfl_xor(m, o));
    float e = __expf(x - m);
    float s = e;
#pragma unroll
    for (int o = 1; o < 16; o <<= 1) s += __shfl_xor(s, o);
    aw1 = e / s;
  }

  // ---- build bv fragments: vin = f2 * leaky(ev1.r + b) ----
  bf16x8 bv[2][4];
#pragma unroll
  for (int ks = 0; ks < 4; ++ks) {
#pragma unroll
    for (int j = 0; j < 8; ++j) {
      int c = ks * 32 + l4 * 8 + j;
      float4 ew = ld_enc(encS, 2, c);
      float e0 = leaky(ew.x * r0[0] + ew.y * r1[0] + ew.z * r2[0] + ew.w);
      float e1 = leaky(ew.x * r0[1] + ew.y * r1[1] + ew.z * r2[1] + ew.w);
      bv[0][ks][j] = (short)f2bf(bf2f((u16)fB[0][ks][j]) * e0);
      bv[1][ks][j] = (short)f2bf(bf2f((u16)fB[1][ks][j]) * e1);
    }
  }

  // ---- GEMM2 (v = Wv @ vin) + ev2 scale + atten-weighted reduce + store ----
#pragma unroll
  for (int mt = 0; mt < 8; ++mt) {
    f32x4 a0 = (f32x4){0.f, 0.f, 0.f, 0.f};
    f32x4 a1 = (f32x4){0.f, 0.f, 0.f, 0.f};
#pragma unroll
    for (int ks = 0; ks < 4; ++ks) {
      bf16x8 af = *(const bf16x8*)&wvm[(mt * 16 + l15) * 128 + ks * 32 + l4 * 8];
      a0 = __builtin_amdgcn_mfma_f32_16x16x32_bf16(af, bv[0][ks], a0, 0, 0, 0);
      a1 = __builtin_amdgcn_mfma_f32_16x16x32_bf16(af, bv[1][ks], a1, 0, 0, 0);
    }
    int m0 = mt * 16 + l4 * 4;
    float s0[4], s1[4];
#pragma unroll
    for (int r = 0; r < 4; ++r) {
      float4 ew = ld_enc(encS, 3, m0 + r);
      float v0 = leaky(ew.x * r0[0] + ew.y * r1[0] + ew.z * r2[0] + ew.w);
      float v1 = leaky(ew.x * r0[1] + ew.y * r1[1] + ew.z * r2[1] + ew.w);
      s0[r] = a0[r] * v0 * aw0;
      s1[r] = a1[r] * v1 * aw1;
    }
#pragma unroll
    for (int o = 1; o < 16; o <<= 1) {
      s0[0] += __shfl_xor(s0[0], o); s0[1] += __shfl_xor(s0[1], o);
      s0[2] += __shfl_xor(s0[2], o); s0[3] += __shfl_xor(s0[3], o);
      s1[0] += __shfl_xor(s1[0], o); s1[1] += __shfl_xor(s1[1], o);
      s1[2] += __shfl_xor(s1[2], o); s1[3] += __shfl_xor(s1[3], o);
    }
    if (l15 == 0) {
      const float4 f1v0 = *(const float4*)&f1s[(w * 2 + 0) * 132 + m0];
      const float4 f1v1 = *(const float4*)&f1s[(w * 2 + 1) * 132 + m0];
      float4 o0 = { s0[0] + f1v0.x, s0[1] + f1v0.y, s0[2] + f1v0.z, s0[3] + f1v0.w };
      float4 o1 = { s1[0] + f1v1.x, s1[1] + f1v1.y, s1[2] + f1v1.z, s1[3] + f1v1.w };
      *(float4*)&outp[(size_t)(b * NN1 + pt0) * 128 + m0] = o0;
      *(float4*)&outp[(size_t)(b * NN1 + pt1) * 128 + m0] = o1;
    }
  }
}

// ---------------------------------------------------------------------------
// FF: h[b][d][n] = ff_w[d,:].feat_new[b][n][:] + ff_b[d]; per-block GN
// partials written non-atomically to pstat[block][8][2].
__global__ __launch_bounds__(256)
void k_ff(const float* __restrict__ xin, const float* __restrict__ ffw,
          const float* __restrict__ ffb, float* __restrict__ hout,
          float* __restrict__ pstat) {
  int t = threadIdx.x, bx = blockIdx.x;
  int b = bx / (NN1 / 32), n0 = (bx % (NN1 / 32)) * 32;
  __shared__ float XT[128][34];
  for (int e = t; e < 4096; e += 256) {
    int c = e & 127, nn = e >> 7;
    XT[c][nn] = xin[(b * NN1 + n0 + nn) * 128 + c];
  }
  __syncthreads();
  int d = t >> 1, nh = t & 1;
  float acc[16];
#pragma unroll
  for (int j = 0; j < 16; ++j) acc[j] = 0.0f;
  for (int c0 = 0; c0 < 128; c0 += 4) {
    float4 w4 = *(const float4*)&ffw[d * 128 + c0];
    const float wa[4] = { w4.x, w4.y, w4.z, w4.w };
#pragma unroll
    for (int k = 0; k < 4; ++k) {
      int c = c0 + k;
#pragma unroll
      for (int j2 = 0; j2 < 8; ++j2) {
        float2 xv = *(const float2*)&XT[c][nh * 16 + j2 * 2];
        acc[j2 * 2 + 0] += wa[k] * xv.x;
        acc[j2 * 2 + 1] += wa[k] * xv.y;
      }
    }
  }
  float bias = ffb[d];
  float ls = 0.0f, lss = 0.0f;
  float out[16];
#pragma unroll
  for (int j = 0; j < 16; ++j) { float h = acc[j] + bias; out[j] = h; ls += h; lss += h * h; }
#pragma unroll
  for (int j4 = 0; j4 < 4; ++j4) {
    float4 o = { out[j4 * 4], out[j4 * 4 + 1], out[j4 * 4 + 2], out[j4 * 4 + 3] };
    *(float4*)&hout[(b * 128 + d) * NN1 + n0 + nh * 16 + j4 * 4] = o;
  }
#pragma unroll
  for (int o = 1; o <= 16; o <<= 1) { ls += __shfl_xor(ls, o); lss += __shfl_xor(lss, o); }
  if ((t & 31) == 0) {
    int g = t >> 5;                  // = d>>4
    pstat[bx * 16 + g * 2 + 0] = ls;
    pstat[bx * 16 + g * 2 + 1] = lss;
  }
}

// Reduce pstat[512][16] -> gnf[2][8][2].
__global__ __launch_bounds__(512)
void k_ffred(const float* __restrict__ pstat, float* __restrict__ gnf) {
  __shared__ float red[512];
  int t = threadIdx.x;
  int b = t >> 8, i = t & 15, chunk = (t >> 4) & 15;
  float s = 0.0f;
#pragma unroll
  for (int k = 0; k < 16; ++k)
    s += pstat[(b * 256 + chunk * 16 + k) * 16 + i];
  red[t] = s;
  __syncthreads();
  if (chunk == 0) {
    float tot = 0.0f;
#pragma unroll
    for (int k2 = 0; k2 < 16; ++k2) tot += red[(b << 8) | (k2 << 4) | i];
    gnf[b * 16 + i] = tot;
  }
}

// Final GN + leaky + f32 store; also writes the xyz1 passthrough (blocks >= 8192).
__global__ __launch_bounds__(256)
void k_final(const float* __restrict__ h, const float* __restrict__ gnf,
             const float* __restrict__ g, const float* __restrict__ bt,
             const float* __restrict__ xyz1, float* __restrict__ out) {
  int bx = blockIdx.x;
  if (bx >= 8192) {
    int e = (bx - 8192) * 256 + threadIdx.x;   // < BB*3*NN1 = 49152
    out[e] = xyz1[e];
    return;
  }
  int e = bx * 256 + threadIdx.x;              // < BB*128*NN1 = 2097152
  int d = (e / NN1) & 127;
  int b = e / (128 * NN1);
  int gi = b * 16 + (d >> 4) * 2;
  float cnt = 16.0f * (float)NN1;
  float mu = gnf[gi] / cnt;
  float var = gnf[gi + 1] / cnt - mu * mu;
  float rs = rsqrtf(var + 1e-5f);
  float x = (h[e] - mu) * rs * g[d] + bt[d];
  out[BB * 3 * NN1 + e] = leaky(x);
}

// ---------------------------------------------------------------------------
extern "C" void kernel_launch(void* const* d_in, const int* in_sizes, int n_in,
                              void* d_out, int out_size, void* d_ws, size_t ws_size,
                              hipStream_t stream) {
  const float* xyz1   = (const float*)d_in[0];
  const float* xyz2   = (const float*)d_in[1];
  const float* feat1  = (const float*)d_in[2];
  const float* feat2  = (const float*)d_in[3];
  const float* pos_w  = (const float*)d_in[4];
  const float* pos_b  = (const float*)d_in[5];
  const float* pos_g  = (const float*)d_in[6];
  const float* pos_bt = (const float*)d_in[7];
  const float* ek_w   = (const float*)d_in[8];
  const float* ek_b   = (const float*)d_in[9];
  const float* eq_w   = (const float*)d_in[10];
  const float* eq_b   = (const float*)d_in[11];
  const float* ev1_w  = (const float*)d_in[12];
  const float* ev1_b  = (const float*)d_in[13];
  const float* ev2_w  = (const float*)d_in[14];
  const float* ev2_b  = (const float*)d_in[15];
  const float* qk_w   = (const float*)d_in[16];
  const float* v_w    = (const float*)d_in[17];
  const float* ff_w   = (const float*)d_in[18];
  const float* ff_b   = (const float*)d_in[19];
  const float* ff_g   = (const float*)d_in[20];
  const float* ff_bt  = (const float*)d_in[21];
  (void)in_sizes; (void)n_in; (void)out_size; (void)ws_size;

  char* ws = (char*)d_ws;          // ~31 MB used
  float*  feat1p   = (float*)(ws);                        // [B][N1][C] f32   8388608 B
  u16*    feat2pb  = (u16*)  (ws + 8388608);              // [B][N2][C] bf16  4194304 B
  float*  attn_out = (float*)(ws + 12582912);             // feat_new (after knn_tmp dead)
  float*  h_ff     = (float*)(ws + 20971520);             // FF out [B][C][N1]
  u32*    knn_tmp  = (u32*)  (ws + 12582912);             // 16 MiB, consumed pre-attn
  int*    idxb     = (int*)  (ws + 29360128);             // [B][N1][16]      1048576 B
  u16*    wqk      = (u16*)  (ws + 30408704);             // bf16 qk_w        32768 B
  u16*    wv       = (u16*)  (ws + 30441472);             // bf16 v_w         32768 B
  float*  mom      = (float*)(ws + 30474240);             // 36 floats (+pad) 160 B
  float2* gnp      = (float2*)(ws + 30474400);            // 32 float2        256 B
  float*  pstat    = (float*)(ws + 30474656);             // 512*16 floats    32768 B
  float*  gnf      = (float*)(ws + 30507424);             // 32 floats        128 B
  float4* px1      = (float4*)(ws + 30507552);            // [B][N1] packed   262144 B
  float4* px2      = (float4*)(ws + 30769696);            // [B][N2] packed   262144 B

  hipMemsetAsync(mom, 0, 160, stream);
  k_prep<<<256, 256, 0, stream>>>(qk_w, v_w, wqk, wv, xyz1, xyz2, px1, px2, mom);
  k_gnstats<<<1, 512, 0, stream>>>(mom, pos_w, pos_b, gnp);
  k_posenc<<<2048, 256, 0, stream>>>(xyz1, xyz2, feat1, feat2, pos_w, pos_b,
                                     pos_g, pos_bt, gnp, feat1p, feat2pb);
  k_knn1<<<1024, 256, 0, stream>>>(px1, px2, knn_tmp);
  k_knn2<<<64, 256, 0, stream>>>(knn_tmp, idxb);
  k_attn<<<2048, 256, 0, stream>>>(xyz1, xyz2, feat1p, feat2pb, idxb, wqk, wv,
                                   eq_w, eq_b, ek_w, ek_b, ev1_w, ev1_b, ev2_w, ev2_b,
                                   attn_out);
  k_ff<<<512, 256, 0, stream>>>(attn_out, ff_w, ff_b, h_ff, pstat);
  k_ffred<<<1, 512, 0, stream>>>(pstat, gnf);
  k_final<<<8384, 256, 0, stream>>>(h_ff, gnf, ff_g, ff_bt, xyz1, (float*)d_out);
}